// Round 8
// baseline (375.411 us; speedup 1.0000x reference)
//
#include <hip/hip_runtime.h>

// Transformer block. B=2 T=2048 E=1024 H=16 DH=64.
// R8: (1) fast exp-based gelu (tanhf was ~5k VALU cyc/wave in ff1 epilogue);
// (2) ff1 -> TN=256 tile (64x128/wave, 42.7 FLOP/LDS-byte vs 32);
// (3) ff2 -> TN=128 split-K=2 (was TN=64, 21.3 FLOP/B). Attention unchanged.

#define En 1024
#define Hn 16
#define DHn 64
#define Bn 2
#define Tn 2048
#define Mrows 4096  // B*T

typedef __attribute__((ext_vector_type(8))) short bf16x8;
typedef __attribute__((ext_vector_type(4))) float f32x4;

__device__ __forceinline__ short f2bf(float f) {
    unsigned u = __float_as_uint(f);
    u += 0x7FFFu + ((u >> 16) & 1u);   // round-to-nearest-even
    return (short)(u >> 16);
}
__device__ __forceinline__ ushort f2bfu(float f) {
    unsigned u = __float_as_uint(f);
    u += 0x7FFFu + ((u >> 16) & 1u);
    return (ushort)(u >> 16);
}

// gelu = 0.5*x*(1+tanh(u)) = x * t/(t+1), t = exp(2u); u = c*x + 0.044715*x^3
__device__ __forceinline__ float gelu_f(float x) {
    float u = 0.79788456080286535588f * x + 0.044715f * x * x * x;
    float t = __expf(2.0f * u);
    return x * t / (t + 1.0f);
}

// async global->LDS, 16B per lane; LDS dest = wave-uniform base + lane*16
__device__ __forceinline__ void load_lds16(const void* g, void* l) {
    __builtin_amdgcn_global_load_lds(
        (const __attribute__((address_space(1))) unsigned int*)(uintptr_t)g,
        (__attribute__((address_space(3))) unsigned int*)(uintptr_t)l,
        16, 0, 0);
}

// ---------------- LayerNorm: one block per row, bf16 out ----------------
__global__ __launch_bounds__(256) void ln_kernel(
    const float* __restrict__ in, const float* __restrict__ sc,
    const float* __restrict__ sh, ushort* __restrict__ out)
{
    int row = blockIdx.x;
    int tid = threadIdx.x;
    float4 v = ((const float4*)(in + (size_t)row * En))[tid];
    float s  = v.x + v.y + v.z + v.w;
    float s2 = v.x*v.x + v.y*v.y + v.z*v.z + v.w*v.w;
    #pragma unroll
    for (int off = 32; off > 0; off >>= 1) {
        s  += __shfl_down(s,  off);
        s2 += __shfl_down(s2, off);
    }
    __shared__ float red[2][4];
    int wave = tid >> 6, lane = tid & 63;
    if (lane == 0) { red[0][wave] = s; red[1][wave] = s2; }
    __syncthreads();
    s  = red[0][0] + red[0][1] + red[0][2] + red[0][3];
    s2 = red[1][0] + red[1][1] + red[1][2] + red[1][3];
    float mean = s * (1.0f / En);
    float var  = s2 * (1.0f / En) - mean * mean;
    float r = rsqrtf(var + 1e-5f);
    float4 scv = ((const float4*)sc)[tid];
    float4 shv = ((const float4*)sh)[tid];
    ushort4 o;
    o.x = f2bfu(scv.x * (v.x - mean) * r + shv.x);
    o.y = f2bfu(scv.y * (v.y - mean) * r + shv.y);
    o.z = f2bfu(scv.z * (v.z - mean) * r + shv.z);
    o.w = f2bfu(scv.w * (v.w - mean) * r + shv.w);
    ((ushort4*)(out + (size_t)row * En))[tid] = o;
}

// ---- fc split-K reduce fused with residual + LN2: one block per row ----
__global__ __launch_bounds__(256) void ln2_fuse(
    const float* __restrict__ P0, const float* __restrict__ P1,
    const float* __restrict__ bias, const float* __restrict__ x,
    const float* __restrict__ sc, const float* __restrict__ sh,
    float* __restrict__ hb, ushort* __restrict__ ynb)
{
    int row = blockIdx.x, tid = threadIdx.x;
    size_t idx = (size_t)row * 256 + tid;
    float4 a  = ((const float4*)P0)[idx];
    float4 b  = ((const float4*)P1)[idx];
    float4 bi = ((const float4*)bias)[tid];
    float4 xr = ((const float4*)x)[idx];
    float4 v;
    v.x = a.x + b.x + bi.x + xr.x;
    v.y = a.y + b.y + bi.y + xr.y;
    v.z = a.z + b.z + bi.z + xr.z;
    v.w = a.w + b.w + bi.w + xr.w;
    ((float4*)hb)[idx] = v;
    float s  = v.x + v.y + v.z + v.w;
    float s2 = v.x*v.x + v.y*v.y + v.z*v.z + v.w*v.w;
    #pragma unroll
    for (int off = 32; off > 0; off >>= 1) {
        s  += __shfl_down(s,  off);
        s2 += __shfl_down(s2, off);
    }
    __shared__ float red[2][4];
    int wave = tid >> 6, lane = tid & 63;
    if (lane == 0) { red[0][wave] = s; red[1][wave] = s2; }
    __syncthreads();
    s  = red[0][0] + red[0][1] + red[0][2] + red[0][3];
    s2 = red[1][0] + red[1][1] + red[1][2] + red[1][3];
    float mean = s * (1.0f / En);
    float var  = s2 * (1.0f / En) - mean * mean;
    float r = rsqrtf(var + 1e-5f);
    float4 scv = ((const float4*)sc)[tid];
    float4 shv = ((const float4*)sh)[tid];
    ushort4 o;
    o.x = f2bfu(scv.x * (v.x - mean) * r + shv.x);
    o.y = f2bfu(scv.y * (v.y - mean) * r + shv.y);
    o.z = f2bfu(scv.z * (v.z - mean) * r + shv.z);
    o.w = f2bfu(scv.w * (v.w - mean) * r + shv.w);
    ((ushort4*)ynb)[idx] = o;
}

// ---- ff2 split-K reduce fused with bias + residual -> out ----
__global__ __launch_bounds__(256) void ff2_reduce(
    const float* __restrict__ P0, const float* __restrict__ P1,
    const float* __restrict__ bias, const float* __restrict__ hb,
    float* __restrict__ out)
{
    int tid = threadIdx.x;
    size_t i = (size_t)blockIdx.x * 256 + tid;
    float4 a  = ((const float4*)P0)[i];
    float4 b  = ((const float4*)P1)[i];
    float4 bi = ((const float4*)bias)[tid];
    float4 h  = ((const float4*)hb)[i];
    float4 o;
    o.x = a.x + b.x + bi.x + h.x;
    o.y = a.y + b.y + bi.y + h.y;
    o.z = a.z + b.z + bi.z + h.z;
    o.w = a.w + b.w + bi.w + h.w;
    ((float4*)out)[i] = o;
}

// ---------------- weight transpose+convert: out[n*K+k] = bf16(in[k*N+n]) ----
__global__ __launch_bounds__(256) void transpose_w(
    const float* __restrict__ in, ushort* __restrict__ out, int K, int N)
{
    __shared__ float t[64][65];
    int k0 = blockIdx.x * 64, n0 = blockIdx.y * 64;
    int tid = threadIdx.x, r = tid >> 4, c4 = (tid & 15) * 4;
    #pragma unroll
    for (int i = 0; i < 4; ++i) {
        float4 v = *(const float4*)(in + (size_t)(k0 + r + i * 16) * N + n0 + c4);
        t[r + i * 16][c4 + 0] = v.x; t[r + i * 16][c4 + 1] = v.y;
        t[r + i * 16][c4 + 2] = v.z; t[r + i * 16][c4 + 3] = v.w;
    }
    __syncthreads();
    #pragma unroll
    for (int i = 0; i < 4; ++i) {
        int n = r + i * 16;
        ushort4 u;
        u.x = f2bfu(t[c4 + 0][n]); u.y = f2bfu(t[c4 + 1][n]);
        u.z = f2bfu(t[c4 + 2][n]); u.w = f2bfu(t[c4 + 3][n]);
        *(ushort4*)(out + (size_t)(n0 + n) * K + k0 + c4) = u;
    }
}

// qkv weights: Wq/Wk/Wv [H][E][DH] -> combined B^T [3072][1024]
__global__ __launch_bounds__(256) void transpose_qkv(
    const float* __restrict__ Wq, const float* __restrict__ Wk,
    const float* __restrict__ Wv, ushort* __restrict__ out)
{
    __shared__ float t[64][65];
    int z = blockIdx.z, sel = z >> 4, h = z & 15;
    const float* in = (sel == 0 ? Wq : sel == 1 ? Wk : Wv) + (size_t)h * En * DHn;
    ushort* o = out + ((size_t)(sel * 1024 + h * 64)) * En;
    int k0 = blockIdx.x * 64;
    int tid = threadIdx.x, r = tid >> 4, c4 = (tid & 15) * 4;
    #pragma unroll
    for (int i = 0; i < 4; ++i) {
        float4 v = *(const float4*)(in + (size_t)(k0 + r + i * 16) * DHn + c4);
        t[r + i * 16][c4 + 0] = v.x; t[r + i * 16][c4 + 1] = v.y;
        t[r + i * 16][c4 + 2] = v.z; t[r + i * 16][c4 + 3] = v.w;
    }
    __syncthreads();
    #pragma unroll
    for (int i = 0; i < 4; ++i) {
        int n = r + i * 16;   // d index 0..63
        ushort4 u;
        u.x = f2bfu(t[c4 + 0][n]); u.y = f2bfu(t[c4 + 1][n]);
        u.z = f2bfu(t[c4 + 2][n]); u.w = f2bfu(t[c4 + 3][n]);
        *(ushort4*)(o + (size_t)n * En + k0 + c4) = u;
    }
}

// ---------------- bf16 MFMA GEMM: C[M][N] = A[M][K] * Bt[N][K]^T -----------
// 128 x TN tile (TN in {64,128,256}), BK=64, slot = j ^ (r&7) XOR swizzle.
// MODE 1: Cb = bf16(gelu(acc + bias))
// MODE 2: qkv scatter: col -> (sel,h,d); q/k (h,b,t,d), v^T [g*64+d][t]
// MODE 3: split-K partial: Cf + z*M*ldc <- raw acc (fp32)
template<int MODE, int TN>
__global__ __launch_bounds__(256) void gemm_bf16(
    const ushort* __restrict__ A, int lda,
    const ushort* __restrict__ Bt, int ldb, int Kloop,
    const float* __restrict__ bias,
    float* __restrict__ Cf, ushort* __restrict__ Cb, int ldc,
    ushort* __restrict__ qo, ushort* __restrict__ ko, ushort* __restrict__ vo)
{
    constexpr int WCN = TN / 2;        // wave n-extent
    constexpr int NI  = WCN / 16;      // 16-col blocks per wave
    constexpr int BIW = TN * 8 / 256;  // B staging instrs per wave
    __shared__ ushort As[128 * 64];
    __shared__ ushort Bs[TN * 64];
    int tid = threadIdx.x, wv = tid >> 6, lid = tid & 63;
    int m0 = blockIdx.x * 128, n0 = blockIdx.y * TN;
    int koff = blockIdx.z * Kloop;
    int wr = wv >> 1, wc = wv & 1;
    int hm = lid & 15, hk = lid >> 4;

    f32x4 acc[4][NI];
    #pragma unroll
    for (int i = 0; i < 4; ++i)
        #pragma unroll
        for (int j = 0; j < NI; ++j) acc[i][j] = (f32x4){0.f, 0.f, 0.f, 0.f};

    const ushort* Abase = A + (size_t)m0 * lda + koff;
    const ushort* Bbase = Bt + (size_t)n0 * ldb + koff;

    for (int k0 = 0; k0 < Kloop; k0 += 64) {
        __syncthreads();
        #pragma unroll
        for (int i = 0; i < 4; ++i) {       // A: 1024 chunks, 4/lane
            int c = wv * 256 + i * 64 + lid;
            int r = c >> 3, s = c & 7;
            int j = s ^ (r & 7);            // source k-chunk for this LDS slot
            load_lds16(Abase + (size_t)r * lda + k0 + j * 8,
                       &As[(wv * 256 + i * 64) * 8]);
        }
        #pragma unroll
        for (int i = 0; i < BIW; ++i) {
            int c = wv * (BIW * 64) + i * 64 + lid;
            int r = c >> 3, s = c & 7;
            int j = s ^ (r & 7);
            load_lds16(Bbase + (size_t)r * ldb + k0 + j * 8,
                       &Bs[(wv * (BIW * 64) + i * 64) * 8]);
        }
        __syncthreads();
        #pragma unroll
        for (int kk = 0; kk < 2; ++kk) {
            bf16x8 af[4], bfr[NI];
            #pragma unroll
            for (int mi = 0; mi < 4; ++mi) {
                int r = wr * 64 + mi * 16 + hm;
                int slot = ((kk << 2) | hk) ^ (r & 7);
                af[mi] = *(const bf16x8*)&As[(r * 8 + slot) * 8];
            }
            #pragma unroll
            for (int ni = 0; ni < NI; ++ni) {
                int r = wc * WCN + ni * 16 + hm;
                int slot = ((kk << 2) | hk) ^ (r & 7);
                bfr[ni] = *(const bf16x8*)&Bs[(r * 8 + slot) * 8];
            }
            #pragma unroll
            for (int mi = 0; mi < 4; ++mi)
                #pragma unroll
                for (int ni = 0; ni < NI; ++ni)
                    acc[mi][ni] = __builtin_amdgcn_mfma_f32_16x16x32_bf16(
                        af[mi], bfr[ni], acc[mi][ni], 0, 0, 0);
        }
    }

    int colbase = n0 + wc * WCN + hm;
    int rowbase = m0 + wr * 64 + hk * 4;
    if (MODE == 1) {
        #pragma unroll
        for (int ni = 0; ni < NI; ++ni) {
            int col = colbase + ni * 16;
            float bb = bias[col];
            #pragma unroll
            for (int mi = 0; mi < 4; ++mi) {
                int row = rowbase + mi * 16;
                #pragma unroll
                for (int r = 0; r < 4; ++r)
                    Cb[(size_t)(row + r) * ldc + col] =
                        f2bfu(gelu_f(acc[mi][ni][r] + bb));
            }
        }
    } else if (MODE == 2) {
        #pragma unroll
        for (int ni = 0; ni < NI; ++ni) {
            int col = colbase + ni * 16;           // 0..3071
            int sel = col >> 10, cc = col & 1023;
            int h = cc >> 6, d = cc & 63;
            if (sel < 2) {
                ushort* outp = (sel == 0 ? qo : ko)
                             + (size_t)h * (Mrows * DHn) + d;
                #pragma unroll
                for (int mi = 0; mi < 4; ++mi) {
                    int row = rowbase + mi * 16;
                    #pragma unroll
                    for (int r = 0; r < 4; ++r)
                        outp[(size_t)(row + r) * DHn] = f2bfu(acc[mi][ni][r]);
                }
            } else {
                // v transposed: vt[(h*2+b)*64 + d][t], t = row & 2047
                #pragma unroll
                for (int mi = 0; mi < 4; ++mi) {
                    int row = rowbase + mi * 16;
                    int bb2 = row >> 11, t = row & 2047;
                    ushort4 u;
                    u.x = f2bfu(acc[mi][ni][0]); u.y = f2bfu(acc[mi][ni][1]);
                    u.z = f2bfu(acc[mi][ni][2]); u.w = f2bfu(acc[mi][ni][3]);
                    *(ushort4*)(vo + ((size_t)((h * 2 + bb2) * 64 + d)) * Tn + t) = u;
                }
            }
        }
    } else {
        float* Cp = Cf + (size_t)blockIdx.z * Mrows * ldc;
        #pragma unroll
        for (int ni = 0; ni < NI; ++ni) {
            int col = colbase + ni * 16;
            #pragma unroll
            for (int mi = 0; mi < 4; ++mi) {
                int row = rowbase + mi * 16;
                #pragma unroll
                for (int r = 0; r < 4; ++r)
                    Cp[(size_t)(row + r) * ldc + col] = acc[mi][ni][r];
            }
        }
    }
}

// ---------------- MFMA flash attention v3 (unchanged) ----------------
__global__ __launch_bounds__(256) void attn_mfma(
    const ushort* __restrict__ q, const ushort* __restrict__ ksrc,
    const ushort* __restrict__ vtsrc, ushort* __restrict__ cat)
{
    int g = blockIdx.x;
    int h = g >> 1, b = g & 1;
    const ushort* qg  = q     + (size_t)g * Tn * DHn;
    const ushort* kg  = ksrc  + (size_t)g * Tn * DHn;
    const ushort* vtg = vtsrc + (size_t)g * DHn * Tn;   // [d][t]
    int tid = threadIdx.x, wave = tid >> 6, lane = tid & 63;
    int m = lane & 15, gq = lane >> 4;

    __shared__ short Ks[4096];      // [key(64)][d(64)] swizzled
    __shared__ short Vt[4096];      // [d(64)][key(64)] swizzled
    __shared__ short Ps[4][1024];   // per-wave [q(16)][key(64)] swizzled

    int R  = tid >> 2;   // staging row 0..63
    int c2 = tid & 3;    // staging 16-elem chunk

    #pragma unroll 1
    for (int phase = 0; phase < 2; ++phase) {
        int qt = phase ? (31 - (int)blockIdx.y) : (int)blockIdx.y;
        int q0 = qt * 64;

        bf16x8 qf[2];
        {
            const ushort* qp = qg + (size_t)(q0 + wave * 16 + m) * DHn + gq * 8;
            qf[0] = *(const bf16x8*)(qp);
            qf[1] = *(const bf16x8*)(qp + 32);
        }
        f32x4 o[4];
        #pragma unroll
        for (int i = 0; i < 4; ++i) o[i] = (f32x4){0.f, 0.f, 0.f, 0.f};
        float lsum[4] = {0.f, 0.f, 0.f, 0.f};

        for (int kt = 0; kt <= qt; ++kt) {
            int k0 = kt * 64;
            __syncthreads();
            {   // stage K tile [key][d] and V^T tile [d][key], both b128 swizzled
                const ushort* ksp = kg  + (size_t)(k0 + R) * DHn + c2 * 16;
                const ushort* vsp = vtg + (size_t)R * Tn + k0 + c2 * 16;
                bf16x8 f0 = *(const bf16x8*)(ksp);
                bf16x8 f1 = *(const bf16x8*)(ksp + 8);
                bf16x8 v0 = *(const bf16x8*)(vsp);
                bf16x8 v1 = *(const bf16x8*)(vsp + 8);
                *(bf16x8*)&Ks[R * 64 + (((c2 * 2    ) ^ (R & 7)) << 3)] = f0;
                *(bf16x8*)&Ks[R * 64 + (((c2 * 2 + 1) ^ (R & 7)) << 3)] = f1;
                *(bf16x8*)&Vt[R * 64 + (((c2 * 2    ) ^ (R & 7)) << 3)] = v0;
                *(bf16x8*)&Vt[R * 64 + (((c2 * 2 + 1) ^ (R & 7)) << 3)] = v1;
            }
            __syncthreads();

            bool diag = (kt == qt);
            float ps[4][4];
            #pragma unroll
            for (int ct = 0; ct < 4; ++ct) {
                if (diag && ct > wave) {   // fully masked sub-tile
                    ps[ct][0] = ps[ct][1] = ps[ct][2] = ps[ct][3] = 0.f;
                    continue;
                }
                f32x4 acc = (f32x4){0.f, 0.f, 0.f, 0.f};
                int row = ct * 16 + m;     // key within tile
                #pragma unroll
                for (int db = 0; db < 2; ++db) {
                    bf16x8 kf = *(const bf16x8*)&Ks[row * 64 + (((db * 4 + gq) ^ (row & 7)) << 3)];
                    acc = __builtin_amdgcn_mfma_f32_16x16x32_bf16(qf[db], kf, acc, 0, 0, 0);
                }
                #pragma unroll
                for (int r = 0; r < 4; ++r) {
                    float p;
                    if (diag && (ct * 16 + m) > (wave * 16 + gq * 4 + r)) {
                        p = 0.f;
                    } else {
                        p = __expf(acc[r] * 0.125f);   // 1/sqrt(64)
                    }
                    ps[ct][r] = p;
                    lsum[r] += p;
                }
            }

            // P (C-layout) -> LDS -> A-layout fragments (per-wave buffer)
            #pragma unroll
            for (int ct = 0; ct < 4; ++ct)
                #pragma unroll
                for (int r = 0; r < 4; ++r) {
                    int row = gq * 4 + r;
                    Ps[wave][row * 64 + ((((ct * 2 + (m >> 3)) ^ (row & 7)) << 3) | (m & 7))] =
                        f2bf(ps[ct][r]);
                }
            bf16x8 pf[2];
            #pragma unroll
            for (int db2 = 0; db2 < 2; ++db2)
                pf[db2] = *(const bf16x8*)&Ps[wave][m * 64 + (((db2 * 4 + gq) ^ (m & 7)) << 3)];

            #pragma unroll
            for (int ct2 = 0; ct2 < 4; ++ct2) {
                int row = ct2 * 16 + m;   // d index
                #pragma unroll
                for (int db2 = 0; db2 < 2; ++db2) {
                    bf16x8 vf = *(const bf16x8*)&Vt[row * 64 + (((db2 * 4 + gq) ^ (row & 7)) << 3)];
                    o[ct2] = __builtin_amdgcn_mfma_f32_16x16x32_bf16(pf[db2], vf, o[ct2], 0, 0, 0);
                }
            }
        }

        // epilogue: reduce l across the 16-lane row group, scale, quirk write
        float inv[4];
        #pragma unroll
        for (int r = 0; r < 4; ++r) {
            float l = lsum[r];
            l += __shfl_xor(l, 1);
            l += __shfl_xor(l, 2);
            l += __shfl_xor(l, 4);
            l += __shfl_xor(l, 8);
            inv[r] = 1.0f / l;
        }
        size_t base = (size_t)b * Tn * En + (size_t)h * 64 + (size_t)qt * En
                    + wave * 16 + gq * 4;
        #pragma unroll
        for (int ct2 = 0; ct2 < 4; ++ct2) {
            int d = ct2 * 16 + m;
            #pragma unroll
            for (int r = 0; r < 4; ++r)
                cat[base + (size_t)d * 32 * En + r] = f2bfu(o[ct2][r] * inv[r]);
        }
    }
}

extern "C" void kernel_launch(void* const* d_in, const int* in_sizes, int n_in,
                              void* d_out, int out_size, void* d_ws, size_t ws_size,
                              hipStream_t stream) {
    const float* x     = (const float*)d_in[0];
    const float* Wq    = (const float*)d_in[1];
    const float* Wk    = (const float*)d_in[2];
    const float* Wv    = (const float*)d_in[3];
    const float* fc_w  = (const float*)d_in[4];
    const float* fc_b  = (const float*)d_in[5];
    const float* ln1_s = (const float*)d_in[6];
    const float* ln1_b = (const float*)d_in[7];
    const float* ln2_s = (const float*)d_in[8];
    const float* ln2_b = (const float*)d_in[9];
    const float* ff_w1 = (const float*)d_in[10];
    const float* ff_b1 = (const float*)d_in[11];
    const float* ff_w2 = (const float*)d_in[12];
    const float* ff_b2 = (const float*)d_in[13];
    float* out = (float*)d_out;
    (void)in_sizes; (void)n_in; (void)out_size; (void)ws_size;

    const size_t MB = 1048576;
    char* w8 = (char*)d_ws;
    ushort* S0   = (ushort*)(w8 + 0 * MB);    // xn_bf / cat_bf (8MB)
    ushort* kb   = (ushort*)(w8 + 8 * MB);    // k bf16 (8MB)
    ushort* vtb  = (ushort*)(w8 + 16 * MB);   // v^T bf16 [g][d][t] (8MB)
    ushort* qb   = (ushort*)(w8 + 24 * MB);   // q bf16 / ynb_bf (8MB)
    float*  hb   = (float*)(w8 + 32 * MB);    // h fp32 (16MB)
    ushort* y1   = (ushort*)(w8 + 48 * MB);   // gelu out bf16 (32MB)
    float*  Pfc  = (float*)(w8 + 48 * MB);    // fc partials 2x16MB (dead before ff1)
    float*  Pff2 = (float*)(w8 + 0 * MB);     // ff2 partials 2x16MB (S0..qb dead)
    ushort* wqkv = (ushort*)(w8 + 80 * MB);   // [3072][1024] (6MB)
    ushort* wfc  = (ushort*)(w8 + 86 * MB);   // [1024][1024] (2MB)
    ushort* wf1  = (ushort*)(w8 + 88 * MB);   // [4096][1024] (8MB)
    ushort* wf2  = (ushort*)(w8 + 96 * MB);   // [1024][4096] (8MB) -> 104MB total

    // weight prep
    transpose_qkv<<<dim3(16, 1, 48), 256, 0, stream>>>(Wq, Wk, Wv, wqkv);
    transpose_w<<<dim3(16, 16), 256, 0, stream>>>(fc_w, wfc, En, En);
    transpose_w<<<dim3(16, 64), 256, 0, stream>>>(ff_w1, wf1, En, 4 * En);
    transpose_w<<<dim3(64, 16), 256, 0, stream>>>(ff_w2, wf2, 4 * En, En);

    // LN1 -> xn (bf16)
    ln_kernel<<<dim3(Mrows), 256, 0, stream>>>(x, ln1_s, ln1_b, S0);
    // QKV: [4096,1024] x [3072,1024]^T, scatter epilogue (v transposed)
    gemm_bf16<2, 128><<<dim3(32, 24), 256, 0, stream>>>(
        S0, En, wqkv, En, En, nullptr, nullptr, nullptr, 0, qb, kb, vtb);
    // attention -> cat (bf16, quirk layout), reuses S0
    attn_mfma<<<dim3(Hn * Bn, 16), 256, 0, stream>>>(qb, kb, vtb, S0);
    // fc split-K=2: partials = cat @ fc_w  (fp32, 2 x 16MB at Pfc)
    gemm_bf16<3, 64><<<dim3(32, 16, 2), 256, 0, stream>>>(
        S0, En, wfc, En, En / 2, nullptr, Pfc, nullptr, En, nullptr, nullptr, nullptr);
    // reduce + bias + resid(x) -> hb, fused LN2 -> ynb (qb)
    ln2_fuse<<<dim3(Mrows), 256, 0, stream>>>(
        Pfc, Pfc + (size_t)Mrows * En, fc_b, x, ln2_s, ln2_b, hb, qb);
    // ff1: y1 = gelu(ynb @ ff_w1 + ff_b1)  (bf16 out), 128x256 tile
    gemm_bf16<1, 256><<<dim3(32, 16), 256, 0, stream>>>(
        qb, En, wf1, En, En, ff_b1, nullptr, y1, 4 * En, nullptr, nullptr, nullptr);
    // ff2 split-K=2: partials = y1 @ ff_w2  (fp32), 128x128 tile
    gemm_bf16<3, 128><<<dim3(32, 8, 2), 256, 0, stream>>>(
        y1, 4 * En, wf2, 4 * En, 2 * En, nullptr, Pff2, nullptr, En, nullptr, nullptr, nullptr);
    // reduce + bias + resid(h) -> out
    ff2_reduce<<<dim3(Mrows), 256, 0, stream>>>(
        Pff2, Pff2 + (size_t)Mrows * En, ff_b2, hb, out);
}

// Round 9
// 353.544 us; speedup vs baseline: 1.0619x; 1.0619x over previous
//
#include <hip/hip_runtime.h>

// Transformer block. B=2 T=2048 E=1024 H=16 DH=64.
// R9: revert R8 tiling (ff1 TN=128 4 blk/CU, ff2 TN=64 splitK2 — blocks/CU
// beats tile intensity in the 2-barrier K-loop), keep fast gelu; QKV epilogue
// coalesced via per-wave LDS bounce (was 64 scalar 2B stores/lane); h in bf16.

#define En 1024
#define Hn 16
#define DHn 64
#define Bn 2
#define Tn 2048
#define Mrows 4096  // B*T

typedef __attribute__((ext_vector_type(8))) short bf16x8;
typedef __attribute__((ext_vector_type(4))) float f32x4;

__device__ __forceinline__ short f2bf(float f) {
    unsigned u = __float_as_uint(f);
    u += 0x7FFFu + ((u >> 16) & 1u);   // round-to-nearest-even
    return (short)(u >> 16);
}
__device__ __forceinline__ ushort f2bfu(float f) {
    unsigned u = __float_as_uint(f);
    u += 0x7FFFu + ((u >> 16) & 1u);
    return (ushort)(u >> 16);
}
__device__ __forceinline__ float bf2f(ushort u) {
    return __uint_as_float((unsigned)u << 16);
}

// gelu = 0.5*x*(1+tanh(u)) = x * t/(t+1), t = exp(2u); u = c*x + 0.044715*x^3
__device__ __forceinline__ float gelu_f(float x) {
    float u = 0.79788456080286535588f * x + 0.044715f * x * x * x;
    float t = __expf(2.0f * u);
    return x * t / (t + 1.0f);
}

// async global->LDS, 16B per lane; LDS dest = wave-uniform base + lane*16
__device__ __forceinline__ void load_lds16(const void* g, void* l) {
    __builtin_amdgcn_global_load_lds(
        (const __attribute__((address_space(1))) unsigned int*)(uintptr_t)g,
        (__attribute__((address_space(3))) unsigned int*)(uintptr_t)l,
        16, 0, 0);
}

// ---------------- LayerNorm: one block per row, bf16 out ----------------
__global__ __launch_bounds__(256) void ln_kernel(
    const float* __restrict__ in, const float* __restrict__ sc,
    const float* __restrict__ sh, ushort* __restrict__ out)
{
    int row = blockIdx.x;
    int tid = threadIdx.x;
    float4 v = ((const float4*)(in + (size_t)row * En))[tid];
    float s  = v.x + v.y + v.z + v.w;
    float s2 = v.x*v.x + v.y*v.y + v.z*v.z + v.w*v.w;
    #pragma unroll
    for (int off = 32; off > 0; off >>= 1) {
        s  += __shfl_down(s,  off);
        s2 += __shfl_down(s2, off);
    }
    __shared__ float red[2][4];
    int wave = tid >> 6, lane = tid & 63;
    if (lane == 0) { red[0][wave] = s; red[1][wave] = s2; }
    __syncthreads();
    s  = red[0][0] + red[0][1] + red[0][2] + red[0][3];
    s2 = red[1][0] + red[1][1] + red[1][2] + red[1][3];
    float mean = s * (1.0f / En);
    float var  = s2 * (1.0f / En) - mean * mean;
    float r = rsqrtf(var + 1e-5f);
    float4 scv = ((const float4*)sc)[tid];
    float4 shv = ((const float4*)sh)[tid];
    ushort4 o;
    o.x = f2bfu(scv.x * (v.x - mean) * r + shv.x);
    o.y = f2bfu(scv.y * (v.y - mean) * r + shv.y);
    o.z = f2bfu(scv.z * (v.z - mean) * r + shv.z);
    o.w = f2bfu(scv.w * (v.w - mean) * r + shv.w);
    ((ushort4*)(out + (size_t)row * En))[tid] = o;
}

// ---- fc split-K reduce fused with residual + LN2; h stored bf16 ----
__global__ __launch_bounds__(256) void ln2_fuse(
    const float* __restrict__ P0, const float* __restrict__ P1,
    const float* __restrict__ bias, const float* __restrict__ x,
    const float* __restrict__ sc, const float* __restrict__ sh,
    ushort* __restrict__ hb, ushort* __restrict__ ynb)
{
    int row = blockIdx.x, tid = threadIdx.x;
    size_t idx = (size_t)row * 256 + tid;
    float4 a  = ((const float4*)P0)[idx];
    float4 b  = ((const float4*)P1)[idx];
    float4 bi = ((const float4*)bias)[tid];
    float4 xr = ((const float4*)x)[idx];
    float4 v;
    v.x = a.x + b.x + bi.x + xr.x;
    v.y = a.y + b.y + bi.y + xr.y;
    v.z = a.z + b.z + bi.z + xr.z;
    v.w = a.w + b.w + bi.w + xr.w;
    ushort4 hv;
    hv.x = f2bfu(v.x); hv.y = f2bfu(v.y); hv.z = f2bfu(v.z); hv.w = f2bfu(v.w);
    ((ushort4*)hb)[idx] = hv;
    float s  = v.x + v.y + v.z + v.w;
    float s2 = v.x*v.x + v.y*v.y + v.z*v.z + v.w*v.w;
    #pragma unroll
    for (int off = 32; off > 0; off >>= 1) {
        s  += __shfl_down(s,  off);
        s2 += __shfl_down(s2, off);
    }
    __shared__ float red[2][4];
    int wave = tid >> 6, lane = tid & 63;
    if (lane == 0) { red[0][wave] = s; red[1][wave] = s2; }
    __syncthreads();
    s  = red[0][0] + red[0][1] + red[0][2] + red[0][3];
    s2 = red[1][0] + red[1][1] + red[1][2] + red[1][3];
    float mean = s * (1.0f / En);
    float var  = s2 * (1.0f / En) - mean * mean;
    float r = rsqrtf(var + 1e-5f);
    float4 scv = ((const float4*)sc)[tid];
    float4 shv = ((const float4*)sh)[tid];
    ushort4 o;
    o.x = f2bfu(scv.x * (v.x - mean) * r + shv.x);
    o.y = f2bfu(scv.y * (v.y - mean) * r + shv.y);
    o.z = f2bfu(scv.z * (v.z - mean) * r + shv.z);
    o.w = f2bfu(scv.w * (v.w - mean) * r + shv.w);
    ((ushort4*)ynb)[idx] = o;
}

// ---- ff2 split-K reduce fused with bias + residual(bf16 h) -> out ----
__global__ __launch_bounds__(256) void ff2_reduce(
    const float* __restrict__ P0, const float* __restrict__ P1,
    const float* __restrict__ bias, const ushort* __restrict__ hb,
    float* __restrict__ out)
{
    int tid = threadIdx.x;
    size_t i = (size_t)blockIdx.x * 256 + tid;
    float4 a  = ((const float4*)P0)[i];
    float4 b  = ((const float4*)P1)[i];
    float4 bi = ((const float4*)bias)[tid];
    ushort4 hu = ((const ushort4*)hb)[i];
    float4 o;
    o.x = a.x + b.x + bi.x + bf2f(hu.x);
    o.y = a.y + b.y + bi.y + bf2f(hu.y);
    o.z = a.z + b.z + bi.z + bf2f(hu.z);
    o.w = a.w + b.w + bi.w + bf2f(hu.w);
    ((float4*)out)[i] = o;
}

// ---------------- weight transpose+convert: out[n*K+k] = bf16(in[k*N+n]) ----
__global__ __launch_bounds__(256) void transpose_w(
    const float* __restrict__ in, ushort* __restrict__ out, int K, int N)
{
    __shared__ float t[64][65];
    int k0 = blockIdx.x * 64, n0 = blockIdx.y * 64;
    int tid = threadIdx.x, r = tid >> 4, c4 = (tid & 15) * 4;
    #pragma unroll
    for (int i = 0; i < 4; ++i) {
        float4 v = *(const float4*)(in + (size_t)(k0 + r + i * 16) * N + n0 + c4);
        t[r + i * 16][c4 + 0] = v.x; t[r + i * 16][c4 + 1] = v.y;
        t[r + i * 16][c4 + 2] = v.z; t[r + i * 16][c4 + 3] = v.w;
    }
    __syncthreads();
    #pragma unroll
    for (int i = 0; i < 4; ++i) {
        int n = r + i * 16;
        ushort4 u;
        u.x = f2bfu(t[c4 + 0][n]); u.y = f2bfu(t[c4 + 1][n]);
        u.z = f2bfu(t[c4 + 2][n]); u.w = f2bfu(t[c4 + 3][n]);
        *(ushort4*)(out + (size_t)(n0 + n) * K + k0 + c4) = u;
    }
}

// qkv weights: Wq/Wk/Wv [H][E][DH] -> combined B^T [3072][1024]
__global__ __launch_bounds__(256) void transpose_qkv(
    const float* __restrict__ Wq, const float* __restrict__ Wk,
    const float* __restrict__ Wv, ushort* __restrict__ out)
{
    __shared__ float t[64][65];
    int z = blockIdx.z, sel = z >> 4, h = z & 15;
    const float* in = (sel == 0 ? Wq : sel == 1 ? Wk : Wv) + (size_t)h * En * DHn;
    ushort* o = out + ((size_t)(sel * 1024 + h * 64)) * En;
    int k0 = blockIdx.x * 64;
    int tid = threadIdx.x, r = tid >> 4, c4 = (tid & 15) * 4;
    #pragma unroll
    for (int i = 0; i < 4; ++i) {
        float4 v = *(const float4*)(in + (size_t)(k0 + r + i * 16) * DHn + c4);
        t[r + i * 16][c4 + 0] = v.x; t[r + i * 16][c4 + 1] = v.y;
        t[r + i * 16][c4 + 2] = v.z; t[r + i * 16][c4 + 3] = v.w;
    }
    __syncthreads();
    #pragma unroll
    for (int i = 0; i < 4; ++i) {
        int n = r + i * 16;   // d index 0..63
        ushort4 u;
        u.x = f2bfu(t[c4 + 0][n]); u.y = f2bfu(t[c4 + 1][n]);
        u.z = f2bfu(t[c4 + 2][n]); u.w = f2bfu(t[c4 + 3][n]);
        *(ushort4*)(o + (size_t)n * En + k0 + c4) = u;
    }
}

// ---------------- bf16 MFMA GEMM: C[M][N] = A[M][K] * Bt[N][K]^T -----------
// 128 x TN tile, BK=64, slot = j ^ (r&7) XOR swizzle.
// MODE 1: Cb = bf16(gelu(acc + bias))
// MODE 2: qkv; per-wave 64x64 quadrant bounced through LDS, coalesced stores:
//         q/k -> (h, b*t, d) row-major; v -> v^T [(h*2+b)*64+d][t]
// MODE 3: split-K partial: Cf + z*M*ldc <- raw acc (fp32)
template<int MODE, int TN>
__global__ __launch_bounds__(256) void gemm_bf16(
    const ushort* __restrict__ A, int lda,
    const ushort* __restrict__ Bt, int ldb, int Kloop,
    const float* __restrict__ bias,
    float* __restrict__ Cf, ushort* __restrict__ Cb, int ldc,
    ushort* __restrict__ qo, ushort* __restrict__ ko, ushort* __restrict__ vo)
{
    constexpr int WCN = TN / 2;        // wave n-extent
    constexpr int NI  = WCN / 16;      // 16-col blocks per wave
    constexpr int BIW = TN * 8 / 256;  // B staging instrs per wave
    constexpr int STAGE = 128 * 64 + TN * 64;
    constexpr int SMEMN = (MODE == 2 && STAGE < 4 * 64 * 68) ? 4 * 64 * 68 : STAGE;
    __shared__ ushort smem[SMEMN];
    ushort* As = smem;
    ushort* Bs = smem + 128 * 64;
    int tid = threadIdx.x, wv = tid >> 6, lid = tid & 63;
    int m0 = blockIdx.x * 128, n0 = blockIdx.y * TN;
    int koff = blockIdx.z * Kloop;
    int wr = wv >> 1, wc = wv & 1;
    int hm = lid & 15, hk = lid >> 4;

    f32x4 acc[4][NI];
    #pragma unroll
    for (int i = 0; i < 4; ++i)
        #pragma unroll
        for (int j = 0; j < NI; ++j) acc[i][j] = (f32x4){0.f, 0.f, 0.f, 0.f};

    const ushort* Abase = A + (size_t)m0 * lda + koff;
    const ushort* Bbase = Bt + (size_t)n0 * ldb + koff;

    for (int k0 = 0; k0 < Kloop; k0 += 64) {
        __syncthreads();
        #pragma unroll
        for (int i = 0; i < 4; ++i) {       // A: 1024 chunks, 4/lane
            int c = wv * 256 + i * 64 + lid;
            int r = c >> 3, s = c & 7;
            int j = s ^ (r & 7);            // source k-chunk for this LDS slot
            load_lds16(Abase + (size_t)r * lda + k0 + j * 8,
                       &As[(wv * 256 + i * 64) * 8]);
        }
        #pragma unroll
        for (int i = 0; i < BIW; ++i) {
            int c = wv * (BIW * 64) + i * 64 + lid;
            int r = c >> 3, s = c & 7;
            int j = s ^ (r & 7);
            load_lds16(Bbase + (size_t)r * ldb + k0 + j * 8,
                       &Bs[(wv * (BIW * 64) + i * 64) * 8]);
        }
        __syncthreads();
        #pragma unroll
        for (int kk = 0; kk < 2; ++kk) {
            bf16x8 af[4], bfr[NI];
            #pragma unroll
            for (int mi = 0; mi < 4; ++mi) {
                int r = wr * 64 + mi * 16 + hm;
                int slot = ((kk << 2) | hk) ^ (r & 7);
                af[mi] = *(const bf16x8*)&As[(r * 8 + slot) * 8];
            }
            #pragma unroll
            for (int ni = 0; ni < NI; ++ni) {
                int r = wc * WCN + ni * 16 + hm;
                int slot = ((kk << 2) | hk) ^ (r & 7);
                bfr[ni] = *(const bf16x8*)&Bs[(r * 8 + slot) * 8];
            }
            #pragma unroll
            for (int mi = 0; mi < 4; ++mi)
                #pragma unroll
                for (int ni = 0; ni < NI; ++ni)
                    acc[mi][ni] = __builtin_amdgcn_mfma_f32_16x16x32_bf16(
                        af[mi], bfr[ni], acc[mi][ni], 0, 0, 0);
        }
    }

    int colbase = n0 + wc * WCN + hm;
    int rowbase = m0 + wr * 64 + hk * 4;
    if (MODE == 1) {
        #pragma unroll
        for (int ni = 0; ni < NI; ++ni) {
            int col = colbase + ni * 16;
            float bb = bias[col];
            #pragma unroll
            for (int mi = 0; mi < 4; ++mi) {
                int row = rowbase + mi * 16;
                #pragma unroll
                for (int r = 0; r < 4; ++r)
                    Cb[(size_t)(row + r) * ldc + col] =
                        f2bfu(gelu_f(acc[mi][ni][r] + bb));
            }
        }
    } else if (MODE == 2) {
        // per-wave 64x64 quadrant -> LDS bounce -> coalesced ushort4 stores
        __syncthreads();   // all waves done reading staging LDS
        ushort* Ls = smem + wv * (64 * 68);
        int col0 = n0 + wc * 64;            // quadrant base (64 cols = 1 head)
        int sel = col0 >> 10, h = (col0 & 1023) >> 6;
        if (sel < 2) {
            // LDS layout [t][d], pitch 68
            #pragma unroll
            for (int ni = 0; ni < NI; ++ni)
                #pragma unroll
                for (int mi = 0; mi < 4; ++mi)
                    #pragma unroll
                    for (int r = 0; r < 4; ++r)
                        Ls[(mi * 16 + hk * 4 + r) * 68 + ni * 16 + hm] =
                            f2bfu(acc[mi][ni][r]);
            ushort* outp = (sel == 0 ? qo : ko) + (size_t)h * (Mrows * DHn);
            int dcol = hm * 4;
            #pragma unroll
            for (int i = 0; i < 16; ++i) {
                int t = hk + i * 4;
                *(ushort4*)(outp + (size_t)(m0 + wr * 64 + t) * DHn + dcol) =
                    *(const ushort4*)&Ls[t * 68 + dcol];
            }
        } else {
            // LDS layout [d][t], pitch 68
            #pragma unroll
            for (int ni = 0; ni < NI; ++ni)
                #pragma unroll
                for (int mi = 0; mi < 4; ++mi)
                    #pragma unroll
                    for (int r = 0; r < 4; ++r)
                        Ls[(ni * 16 + hm) * 68 + mi * 16 + hk * 4 + r] =
                            f2bfu(acc[mi][ni][r]);
            int bb2 = m0 >> 11;                 // batch of this row-tile
            int t0 = (m0 & 2047) + wr * 64;
            ushort* outp = vo + ((size_t)((h * 2 + bb2) * 64)) * Tn + t0;
            int tcol = hm * 4;
            #pragma unroll
            for (int i = 0; i < 16; ++i) {
                int d = hk + i * 4;
                *(ushort4*)(outp + (size_t)d * Tn + tcol) =
                    *(const ushort4*)&Ls[d * 68 + tcol];
            }
        }
    } else {
        float* Cp = Cf + (size_t)blockIdx.z * Mrows * ldc;
        #pragma unroll
        for (int ni = 0; ni < NI; ++ni) {
            int col = colbase + ni * 16;
            #pragma unroll
            for (int mi = 0; mi < 4; ++mi) {
                int row = rowbase + mi * 16;
                #pragma unroll
                for (int r = 0; r < 4; ++r)
                    Cp[(size_t)(row + r) * ldc + col] = acc[mi][ni][r];
            }
        }
    }
}

// ---------------- MFMA flash attention v3 (unchanged) ----------------
__global__ __launch_bounds__(256) void attn_mfma(
    const ushort* __restrict__ q, const ushort* __restrict__ ksrc,
    const ushort* __restrict__ vtsrc, ushort* __restrict__ cat)
{
    int g = blockIdx.x;
    int h = g >> 1, b = g & 1;
    const ushort* qg  = q     + (size_t)g * Tn * DHn;
    const ushort* kg  = ksrc  + (size_t)g * Tn * DHn;
    const ushort* vtg = vtsrc + (size_t)g * DHn * Tn;   // [d][t]
    int tid = threadIdx.x, wave = tid >> 6, lane = tid & 63;
    int m = lane & 15, gq = lane >> 4;

    __shared__ short Ks[4096];      // [key(64)][d(64)] swizzled
    __shared__ short Vt[4096];      // [d(64)][key(64)] swizzled
    __shared__ short Ps[4][1024];   // per-wave [q(16)][key(64)] swizzled

    int R  = tid >> 2;   // staging row 0..63
    int c2 = tid & 3;    // staging 16-elem chunk

    #pragma unroll 1
    for (int phase = 0; phase < 2; ++phase) {
        int qt = phase ? (31 - (int)blockIdx.y) : (int)blockIdx.y;
        int q0 = qt * 64;

        bf16x8 qf[2];
        {
            const ushort* qp = qg + (size_t)(q0 + wave * 16 + m) * DHn + gq * 8;
            qf[0] = *(const bf16x8*)(qp);
            qf[1] = *(const bf16x8*)(qp + 32);
        }
        f32x4 o[4];
        #pragma unroll
        for (int i = 0; i < 4; ++i) o[i] = (f32x4){0.f, 0.f, 0.f, 0.f};
        float lsum[4] = {0.f, 0.f, 0.f, 0.f};

        for (int kt = 0; kt <= qt; ++kt) {
            int k0 = kt * 64;
            __syncthreads();
            {   // stage K tile [key][d] and V^T tile [d][key], both b128 swizzled
                const ushort* ksp = kg  + (size_t)(k0 + R) * DHn + c2 * 16;
                const ushort* vsp = vtg + (size_t)R * Tn + k0 + c2 * 16;
                bf16x8 f0 = *(const bf16x8*)(ksp);
                bf16x8 f1 = *(const bf16x8*)(ksp + 8);
                bf16x8 v0 = *(const bf16x8*)(vsp);
                bf16x8 v1 = *(const bf16x8*)(vsp + 8);
                *(bf16x8*)&Ks[R * 64 + (((c2 * 2    ) ^ (R & 7)) << 3)] = f0;
                *(bf16x8*)&Ks[R * 64 + (((c2 * 2 + 1) ^ (R & 7)) << 3)] = f1;
                *(bf16x8*)&Vt[R * 64 + (((c2 * 2    ) ^ (R & 7)) << 3)] = v0;
                *(bf16x8*)&Vt[R * 64 + (((c2 * 2 + 1) ^ (R & 7)) << 3)] = v1;
            }
            __syncthreads();

            bool diag = (kt == qt);
            float ps[4][4];
            #pragma unroll
            for (int ct = 0; ct < 4; ++ct) {
                if (diag && ct > wave) {   // fully masked sub-tile
                    ps[ct][0] = ps[ct][1] = ps[ct][2] = ps[ct][3] = 0.f;
                    continue;
                }
                f32x4 acc = (f32x4){0.f, 0.f, 0.f, 0.f};
                int row = ct * 16 + m;     // key within tile
                #pragma unroll
                for (int db = 0; db < 2; ++db) {
                    bf16x8 kf = *(const bf16x8*)&Ks[row * 64 + (((db * 4 + gq) ^ (row & 7)) << 3)];
                    acc = __builtin_amdgcn_mfma_f32_16x16x32_bf16(qf[db], kf, acc, 0, 0, 0);
                }
                #pragma unroll
                for (int r = 0; r < 4; ++r) {
                    float p;
                    if (diag && (ct * 16 + m) > (wave * 16 + gq * 4 + r)) {
                        p = 0.f;
                    } else {
                        p = __expf(acc[r] * 0.125f);   // 1/sqrt(64)
                    }
                    ps[ct][r] = p;
                    lsum[r] += p;
                }
            }

            // P (C-layout) -> LDS -> A-layout fragments (per-wave buffer)
            #pragma unroll
            for (int ct = 0; ct < 4; ++ct)
                #pragma unroll
                for (int r = 0; r < 4; ++r) {
                    int row = gq * 4 + r;
                    Ps[wave][row * 64 + ((((ct * 2 + (m >> 3)) ^ (row & 7)) << 3) | (m & 7))] =
                        f2bf(ps[ct][r]);
                }
            bf16x8 pf[2];
            #pragma unroll
            for (int db2 = 0; db2 < 2; ++db2)
                pf[db2] = *(const bf16x8*)&Ps[wave][m * 64 + (((db2 * 4 + gq) ^ (m & 7)) << 3)];

            #pragma unroll
            for (int ct2 = 0; ct2 < 4; ++ct2) {
                int row = ct2 * 16 + m;   // d index
                #pragma unroll
                for (int db2 = 0; db2 < 2; ++db2) {
                    bf16x8 vf = *(const bf16x8*)&Vt[row * 64 + (((db2 * 4 + gq) ^ (row & 7)) << 3)];
                    o[ct2] = __builtin_amdgcn_mfma_f32_16x16x32_bf16(pf[db2], vf, o[ct2], 0, 0, 0);
                }
            }
        }

        // epilogue: reduce l across the 16-lane row group, scale, quirk write
        float inv[4];
        #pragma unroll
        for (int r = 0; r < 4; ++r) {
            float l = lsum[r];
            l += __shfl_xor(l, 1);
            l += __shfl_xor(l, 2);
            l += __shfl_xor(l, 4);
            l += __shfl_xor(l, 8);
            inv[r] = 1.0f / l;
        }
        size_t base = (size_t)b * Tn * En + (size_t)h * 64 + (size_t)qt * En
                    + wave * 16 + gq * 4;
        #pragma unroll
        for (int ct2 = 0; ct2 < 4; ++ct2) {
            int d = ct2 * 16 + m;
            #pragma unroll
            for (int r = 0; r < 4; ++r)
                cat[base + (size_t)d * 32 * En + r] = f2bfu(o[ct2][r] * inv[r]);
        }
    }
}

extern "C" void kernel_launch(void* const* d_in, const int* in_sizes, int n_in,
                              void* d_out, int out_size, void* d_ws, size_t ws_size,
                              hipStream_t stream) {
    const float* x     = (const float*)d_in[0];
    const float* Wq    = (const float*)d_in[1];
    const float* Wk    = (const float*)d_in[2];
    const float* Wv    = (const float*)d_in[3];
    const float* fc_w  = (const float*)d_in[4];
    const float* fc_b  = (const float*)d_in[5];
    const float* ln1_s = (const float*)d_in[6];
    const float* ln1_b = (const float*)d_in[7];
    const float* ln2_s = (const float*)d_in[8];
    const float* ln2_b = (const float*)d_in[9];
    const float* ff_w1 = (const float*)d_in[10];
    const float* ff_b1 = (const float*)d_in[11];
    const float* ff_w2 = (const float*)d_in[12];
    const float* ff_b2 = (const float*)d_in[13];
    float* out = (float*)d_out;
    (void)in_sizes; (void)n_in; (void)out_size; (void)ws_size;

    const size_t MB = 1048576;
    char* w8 = (char*)d_ws;
    ushort* S0   = (ushort*)(w8 + 0 * MB);    // xn_bf / cat_bf (8MB)
    ushort* kb   = (ushort*)(w8 + 8 * MB);    // k bf16 (8MB)
    ushort* vtb  = (ushort*)(w8 + 16 * MB);   // v^T bf16 [g][d][t] (8MB)
    ushort* qb   = (ushort*)(w8 + 24 * MB);   // q bf16 / ynb_bf (8MB)
    ushort* hb   = (ushort*)(w8 + 32 * MB);   // h bf16 (8MB)
    ushort* y1   = (ushort*)(w8 + 48 * MB);   // gelu out bf16 (32MB)
    float*  Pfc  = (float*)(w8 + 48 * MB);    // fc partials 2x16MB (dead before ff1)
    float*  Pff2 = (float*)(w8 + 0 * MB);     // ff2 partials 2x16MB (S0..qb dead)
    ushort* wqkv = (ushort*)(w8 + 80 * MB);   // [3072][1024] (6MB)
    ushort* wfc  = (ushort*)(w8 + 86 * MB);   // [1024][1024] (2MB)
    ushort* wf1  = (ushort*)(w8 + 88 * MB);   // [4096][1024] (8MB)
    ushort* wf2  = (ushort*)(w8 + 96 * MB);   // [1024][4096] (8MB) -> 104MB total

    // weight prep
    transpose_qkv<<<dim3(16, 1, 48), 256, 0, stream>>>(Wq, Wk, Wv, wqkv);
    transpose_w<<<dim3(16, 16), 256, 0, stream>>>(fc_w, wfc, En, En);
    transpose_w<<<dim3(16, 64), 256, 0, stream>>>(ff_w1, wf1, En, 4 * En);
    transpose_w<<<dim3(64, 16), 256, 0, stream>>>(ff_w2, wf2, 4 * En, En);

    // LN1 -> xn (bf16)
    ln_kernel<<<dim3(Mrows), 256, 0, stream>>>(x, ln1_s, ln1_b, S0);
    // QKV: [4096,1024] x [3072,1024]^T, LDS-bounced coalesced epilogue
    gemm_bf16<2, 128><<<dim3(32, 24), 256, 0, stream>>>(
        S0, En, wqkv, En, En, nullptr, nullptr, nullptr, 0, qb, kb, vtb);
    // attention -> cat (bf16, quirk layout), reuses S0
    attn_mfma<<<dim3(Hn * Bn, 16), 256, 0, stream>>>(qb, kb, vtb, S0);
    // fc split-K=2: partials = cat @ fc_w  (fp32, 2 x 16MB at Pfc)
    gemm_bf16<3, 64><<<dim3(32, 16, 2), 256, 0, stream>>>(
        S0, En, wfc, En, En / 2, nullptr, Pfc, nullptr, En, nullptr, nullptr, nullptr);
    // reduce + bias + resid(x) -> hb (bf16), fused LN2 -> ynb (qb)
    ln2_fuse<<<dim3(Mrows), 256, 0, stream>>>(
        Pfc, Pfc + (size_t)Mrows * En, fc_b, x, ln2_s, ln2_b, hb, qb);
    // ff1: y1 = gelu(ynb @ ff_w1 + ff_b1)  (bf16 out), 128x128 tile, 1024 blk
    gemm_bf16<1, 128><<<dim3(32, 32), 256, 0, stream>>>(
        qb, En, wf1, En, En, ff_b1, nullptr, y1, 4 * En, nullptr, nullptr, nullptr);
    // ff2 split-K=2: partials = y1 @ ff_w2  (fp32), TN=64 -> 1024 blocks
    gemm_bf16<3, 64><<<dim3(32, 16, 2), 256, 0, stream>>>(
        y1, 4 * En, wf2, 4 * En, 2 * En, nullptr, Pff2, nullptr, En, nullptr, nullptr, nullptr);
    // reduce + bias + resid(h bf16) -> out
    ff2_reduce<<<dim3(Mrows), 256, 0, stream>>>(
        Pff2, Pff2 + (size_t)Mrows * En, ff_b2, hb, out);
}

// Round 11
// 352.974 us; speedup vs baseline: 1.0636x; 1.0016x over previous
//
#include <hip/hip_runtime.h>

// Transformer block. B=2 T=2048 E=1024 H=16 DH=64.
// R11: fix ff1 call arity (stale nullptr from removed Cf param). Otherwise
// identical to R10: bf16 split-K partials + LDS-bounced full-line stores,
// merged weight prep, bf16 h residual.

#define En 1024
#define Hn 16
#define DHn 64
#define Bn 2
#define Tn 2048
#define Mrows 4096  // B*T

typedef __attribute__((ext_vector_type(8))) short bf16x8;
typedef __attribute__((ext_vector_type(4))) float f32x4;

__device__ __forceinline__ short f2bf(float f) {
    unsigned u = __float_as_uint(f);
    u += 0x7FFFu + ((u >> 16) & 1u);   // round-to-nearest-even
    return (short)(u >> 16);
}
__device__ __forceinline__ ushort f2bfu(float f) {
    unsigned u = __float_as_uint(f);
    u += 0x7FFFu + ((u >> 16) & 1u);
    return (ushort)(u >> 16);
}
__device__ __forceinline__ float bf2f(ushort u) {
    return __uint_as_float((unsigned)u << 16);
}

// gelu = 0.5*x*(1+tanh(u)) = x * t/(t+1), t = exp(2u); u = c*x + 0.044715*x^3
__device__ __forceinline__ float gelu_f(float x) {
    float u = 0.79788456080286535588f * x + 0.044715f * x * x * x;
    float t = __expf(2.0f * u);
    return x * t / (t + 1.0f);
}

// async global->LDS, 16B per lane; LDS dest = wave-uniform base + lane*16
__device__ __forceinline__ void load_lds16(const void* g, void* l) {
    __builtin_amdgcn_global_load_lds(
        (const __attribute__((address_space(1))) unsigned int*)(uintptr_t)g,
        (__attribute__((address_space(3))) unsigned int*)(uintptr_t)l,
        16, 0, 0);
}

// ---------------- LayerNorm: one block per row, bf16 out ----------------
__global__ __launch_bounds__(256) void ln_kernel(
    const float* __restrict__ in, const float* __restrict__ sc,
    const float* __restrict__ sh, ushort* __restrict__ out)
{
    int row = blockIdx.x;
    int tid = threadIdx.x;
    float4 v = ((const float4*)(in + (size_t)row * En))[tid];
    float s  = v.x + v.y + v.z + v.w;
    float s2 = v.x*v.x + v.y*v.y + v.z*v.z + v.w*v.w;
    #pragma unroll
    for (int off = 32; off > 0; off >>= 1) {
        s  += __shfl_down(s,  off);
        s2 += __shfl_down(s2, off);
    }
    __shared__ float red[2][4];
    int wave = tid >> 6, lane = tid & 63;
    if (lane == 0) { red[0][wave] = s; red[1][wave] = s2; }
    __syncthreads();
    s  = red[0][0] + red[0][1] + red[0][2] + red[0][3];
    s2 = red[1][0] + red[1][1] + red[1][2] + red[1][3];
    float mean = s * (1.0f / En);
    float var  = s2 * (1.0f / En) - mean * mean;
    float r = rsqrtf(var + 1e-5f);
    float4 scv = ((const float4*)sc)[tid];
    float4 shv = ((const float4*)sh)[tid];
    ushort4 o;
    o.x = f2bfu(scv.x * (v.x - mean) * r + shv.x);
    o.y = f2bfu(scv.y * (v.y - mean) * r + shv.y);
    o.z = f2bfu(scv.z * (v.z - mean) * r + shv.z);
    o.w = f2bfu(scv.w * (v.w - mean) * r + shv.w);
    ((ushort4*)(out + (size_t)row * En))[tid] = o;
}

// ---- fc split-K reduce (bf16 partials) + residual + LN2; h stored bf16 ----
__global__ __launch_bounds__(256) void ln2_fuse(
    const ushort* __restrict__ P0, const ushort* __restrict__ P1,
    const float* __restrict__ bias, const float* __restrict__ x,
    const float* __restrict__ sc, const float* __restrict__ sh,
    ushort* __restrict__ hb, ushort* __restrict__ ynb)
{
    int row = blockIdx.x, tid = threadIdx.x;
    size_t idx = (size_t)row * 256 + tid;
    ushort4 a = ((const ushort4*)P0)[idx];
    ushort4 b = ((const ushort4*)P1)[idx];
    float4 bi = ((const float4*)bias)[tid];
    float4 xr = ((const float4*)x)[idx];
    float4 v;
    v.x = bf2f(a.x) + bf2f(b.x) + bi.x + xr.x;
    v.y = bf2f(a.y) + bf2f(b.y) + bi.y + xr.y;
    v.z = bf2f(a.z) + bf2f(b.z) + bi.z + xr.z;
    v.w = bf2f(a.w) + bf2f(b.w) + bi.w + xr.w;
    ushort4 hv;
    hv.x = f2bfu(v.x); hv.y = f2bfu(v.y); hv.z = f2bfu(v.z); hv.w = f2bfu(v.w);
    ((ushort4*)hb)[idx] = hv;
    float s  = v.x + v.y + v.z + v.w;
    float s2 = v.x*v.x + v.y*v.y + v.z*v.z + v.w*v.w;
    #pragma unroll
    for (int off = 32; off > 0; off >>= 1) {
        s  += __shfl_down(s,  off);
        s2 += __shfl_down(s2, off);
    }
    __shared__ float red[2][4];
    int wave = tid >> 6, lane = tid & 63;
    if (lane == 0) { red[0][wave] = s; red[1][wave] = s2; }
    __syncthreads();
    s  = red[0][0] + red[0][1] + red[0][2] + red[0][3];
    s2 = red[1][0] + red[1][1] + red[1][2] + red[1][3];
    float mean = s * (1.0f / En);
    float var  = s2 * (1.0f / En) - mean * mean;
    float r = rsqrtf(var + 1e-5f);
    float4 scv = ((const float4*)sc)[tid];
    float4 shv = ((const float4*)sh)[tid];
    ushort4 o;
    o.x = f2bfu(scv.x * (v.x - mean) * r + shv.x);
    o.y = f2bfu(scv.y * (v.y - mean) * r + shv.y);
    o.z = f2bfu(scv.z * (v.z - mean) * r + shv.z);
    o.w = f2bfu(scv.w * (v.w - mean) * r + shv.w);
    ((ushort4*)ynb)[idx] = o;
}

// ---- ff2 split-K reduce (bf16 partials) + bias + residual(bf16 h) -> out ----
__global__ __launch_bounds__(256) void ff2_reduce(
    const ushort* __restrict__ P0, const ushort* __restrict__ P1,
    const float* __restrict__ bias, const ushort* __restrict__ hb,
    float* __restrict__ out)
{
    int tid = threadIdx.x;
    size_t i = (size_t)blockIdx.x * 256 + tid;
    ushort4 a = ((const ushort4*)P0)[i];
    ushort4 b = ((const ushort4*)P1)[i];
    float4 bi = ((const float4*)bias)[tid];
    ushort4 hu = ((const ushort4*)hb)[i];
    float4 o;
    o.x = bf2f(a.x) + bf2f(b.x) + bi.x + bf2f(hu.x);
    o.y = bf2f(a.y) + bf2f(b.y) + bi.y + bf2f(hu.y);
    o.z = bf2f(a.z) + bf2f(b.z) + bi.z + bf2f(hu.z);
    o.w = bf2f(a.w) + bf2f(b.w) + bi.w + bf2f(hu.w);
    ((float4*)out)[i] = o;
}

// ------- unified weight prep: all four transposes in one dispatch ---------
// out[n*ldo + k] = bf16(in[k*N + n]), 64x64 tiles.
__global__ __launch_bounds__(256) void prep_w(
    const float* __restrict__ Wq, const float* __restrict__ Wk,
    const float* __restrict__ Wv, const float* __restrict__ fc_w,
    const float* __restrict__ ff_w1, const float* __restrict__ ff_w2,
    ushort* __restrict__ wqkv, ushort* __restrict__ wfc,
    ushort* __restrict__ wf1, ushort* __restrict__ wf2)
{
    int bid = blockIdx.x;
    const float* in; ushort* out; int N, ldo, k0, n0;
    if (bid < 768) {                       // qkv: 48 z-slices x 16 k-blocks
        int z = bid >> 4, kb = bid & 15;
        int sel = z / 16, h = z % 16;
        in  = (sel == 0 ? Wq : sel == 1 ? Wk : Wv) + (size_t)h * En * DHn;
        out = wqkv + (size_t)(sel * 1024 + h * 64) * En;
        N = DHn; ldo = En; k0 = kb * 64; n0 = 0;
    } else if (bid < 1024) {               // fc_w: 16x16
        int b2 = bid - 768;
        in = fc_w; out = wfc; N = En; ldo = En;
        k0 = (b2 & 15) * 64; n0 = (b2 >> 4) * 64;
    } else if (bid < 2048) {               // ff_w1: 16 k x 64 n
        int b2 = bid - 1024;
        in = ff_w1; out = wf1; N = 4 * En; ldo = En;
        k0 = (b2 & 15) * 64; n0 = (b2 >> 4) * 64;
    } else {                               // ff_w2: 64 k x 16 n
        int b2 = bid - 2048;
        in = ff_w2; out = wf2; N = En; ldo = 4 * En;
        k0 = (b2 & 63) * 64; n0 = (b2 >> 6) * 64;
    }
    __shared__ float t[64][65];
    int tid = threadIdx.x, r = tid >> 4, c4 = (tid & 15) * 4;
    #pragma unroll
    for (int i = 0; i < 4; ++i) {
        float4 v = *(const float4*)(in + (size_t)(k0 + r + i * 16) * N + n0 + c4);
        t[r + i * 16][c4 + 0] = v.x; t[r + i * 16][c4 + 1] = v.y;
        t[r + i * 16][c4 + 2] = v.z; t[r + i * 16][c4 + 3] = v.w;
    }
    __syncthreads();
    #pragma unroll
    for (int i = 0; i < 4; ++i) {
        int n = r + i * 16;
        ushort4 u;
        u.x = f2bfu(t[c4 + 0][n]); u.y = f2bfu(t[c4 + 1][n]);
        u.z = f2bfu(t[c4 + 2][n]); u.w = f2bfu(t[c4 + 3][n]);
        *(ushort4*)(out + (size_t)(n0 + n) * ldo + k0 + c4) = u;
    }
}

// ---------------- bf16 MFMA GEMM: C[M][N] = A[M][K] * Bt[N][K]^T -----------
// 128 x TN tile, BK=64, slot = j ^ (r&7) XOR swizzle.
// MODE 1: Cb = bf16(gelu(acc + bias))
// MODE 2: qkv; per-wave 64x64 quadrant bounced through LDS, coalesced stores
// MODE 3: split-K partial in bf16: Cb + z*M*ldc, LDS-bounced full-line stores
template<int MODE, int TN>
__global__ __launch_bounds__(256) void gemm_bf16(
    const ushort* __restrict__ A, int lda,
    const ushort* __restrict__ Bt, int ldb, int Kloop,
    const float* __restrict__ bias,
    ushort* __restrict__ Cb, int ldc,
    ushort* __restrict__ qo, ushort* __restrict__ ko, ushort* __restrict__ vo)
{
    constexpr int WCN = TN / 2;        // wave n-extent
    constexpr int NI  = WCN / 16;      // 16-col blocks per wave
    constexpr int BIW = TN * 8 / 256;  // B staging instrs per wave
    constexpr int STAGE = 128 * 64 + TN * 64;
    constexpr int BOUNCE = (MODE == 2) ? 4 * 64 * 68 : (MODE == 3 ? 128 * 68 : 0);
    constexpr int SMEMN = STAGE > BOUNCE ? STAGE : BOUNCE;
    __shared__ ushort smem[SMEMN];
    ushort* As = smem;
    ushort* Bs = smem + 128 * 64;
    int tid = threadIdx.x, wv = tid >> 6, lid = tid & 63;
    int m0 = blockIdx.x * 128, n0 = blockIdx.y * TN;
    int koff = blockIdx.z * Kloop;
    int wr = wv >> 1, wc = wv & 1;
    int hm = lid & 15, hk = lid >> 4;

    f32x4 acc[4][NI];
    #pragma unroll
    for (int i = 0; i < 4; ++i)
        #pragma unroll
        for (int j = 0; j < NI; ++j) acc[i][j] = (f32x4){0.f, 0.f, 0.f, 0.f};

    const ushort* Abase = A + (size_t)m0 * lda + koff;
    const ushort* Bbase = Bt + (size_t)n0 * ldb + koff;

    for (int k0 = 0; k0 < Kloop; k0 += 64) {
        __syncthreads();
        #pragma unroll
        for (int i = 0; i < 4; ++i) {       // A: 1024 chunks, 4/lane
            int c = wv * 256 + i * 64 + lid;
            int r = c >> 3, s = c & 7;
            int j = s ^ (r & 7);            // source k-chunk for this LDS slot
            load_lds16(Abase + (size_t)r * lda + k0 + j * 8,
                       &As[(wv * 256 + i * 64) * 8]);
        }
        #pragma unroll
        for (int i = 0; i < BIW; ++i) {
            int c = wv * (BIW * 64) + i * 64 + lid;
            int r = c >> 3, s = c & 7;
            int j = s ^ (r & 7);
            load_lds16(Bbase + (size_t)r * ldb + k0 + j * 8,
                       &Bs[(wv * (BIW * 64) + i * 64) * 8]);
        }
        __syncthreads();
        #pragma unroll
        for (int kk = 0; kk < 2; ++kk) {
            bf16x8 af[4], bfr[NI];
            #pragma unroll
            for (int mi = 0; mi < 4; ++mi) {
                int r = wr * 64 + mi * 16 + hm;
                int slot = ((kk << 2) | hk) ^ (r & 7);
                af[mi] = *(const bf16x8*)&As[(r * 8 + slot) * 8];
            }
            #pragma unroll
            for (int ni = 0; ni < NI; ++ni) {
                int r = wc * WCN + ni * 16 + hm;
                int slot = ((kk << 2) | hk) ^ (r & 7);
                bfr[ni] = *(const bf16x8*)&Bs[(r * 8 + slot) * 8];
            }
            #pragma unroll
            for (int mi = 0; mi < 4; ++mi)
                #pragma unroll
                for (int ni = 0; ni < NI; ++ni)
                    acc[mi][ni] = __builtin_amdgcn_mfma_f32_16x16x32_bf16(
                        af[mi], bfr[ni], acc[mi][ni], 0, 0, 0);
        }
    }

    int colbase = n0 + wc * WCN + hm;
    int rowbase = m0 + wr * 64 + hk * 4;
    if (MODE == 1) {
        #pragma unroll
        for (int ni = 0; ni < NI; ++ni) {
            int col = colbase + ni * 16;
            float bb = bias[col];
            #pragma unroll
            for (int mi = 0; mi < 4; ++mi) {
                int row = rowbase + mi * 16;
                #pragma unroll
                for (int r = 0; r < 4; ++r)
                    Cb[(size_t)(row + r) * ldc + col] =
                        f2bfu(gelu_f(acc[mi][ni][r] + bb));
            }
        }
    } else if (MODE == 2) {
        // per-wave 64x64 quadrant -> LDS bounce -> coalesced ushort4 stores
        __syncthreads();   // all waves done reading staging LDS
        ushort* Ls = smem + wv * (64 * 68);
        int col0 = n0 + wc * 64;            // quadrant base (64 cols = 1 head)
        int sel = col0 >> 10, h = (col0 & 1023) >> 6;
        if (sel < 2) {
            // LDS layout [t][d], pitch 68
            #pragma unroll
            for (int ni = 0; ni < NI; ++ni)
                #pragma unroll
                for (int mi = 0; mi < 4; ++mi)
                    #pragma unroll
                    for (int r = 0; r < 4; ++r)
                        Ls[(mi * 16 + hk * 4 + r) * 68 + ni * 16 + hm] =
                            f2bfu(acc[mi][ni][r]);
            ushort* outp = (sel == 0 ? qo : ko) + (size_t)h * (Mrows * DHn);
            int dcol = hm * 4;
            #pragma unroll
            for (int i = 0; i < 16; ++i) {
                int t = hk + i * 4;
                *(ushort4*)(outp + (size_t)(m0 + wr * 64 + t) * DHn + dcol) =
                    *(const ushort4*)&Ls[t * 68 + dcol];
            }
        } else {
            // LDS layout [d][t], pitch 68
            #pragma unroll
            for (int ni = 0; ni < NI; ++ni)
                #pragma unroll
                for (int mi = 0; mi < 4; ++mi)
                    #pragma unroll
                    for (int r = 0; r < 4; ++r)
                        Ls[(ni * 16 + hm) * 68 + mi * 16 + hk * 4 + r] =
                            f2bfu(acc[mi][ni][r]);
            int bb2 = m0 >> 11;                 // batch of this row-tile
            int t0 = (m0 & 2047) + wr * 64;
            ushort* outp = vo + ((size_t)((h * 2 + bb2) * 64)) * Tn + t0;
            int tcol = hm * 4;
            #pragma unroll
            for (int i = 0; i < 16; ++i) {
                int d = hk + i * 4;
                *(ushort4*)(outp + (size_t)d * Tn + tcol) =
                    *(const ushort4*)&Ls[d * 68 + tcol];
            }
        }
    } else {
        // bf16 partials, bounced through LDS for full-line coalesced stores
        __syncthreads();   // staging LDS reads complete
        ushort* Ls = smem; // [128][TN] pitch 68 (TN==64)
        #pragma unroll
        for (int ni = 0; ni < NI; ++ni)
            #pragma unroll
            for (int mi = 0; mi < 4; ++mi)
                #pragma unroll
                for (int r = 0; r < 4; ++r)
                    Ls[(wr * 64 + mi * 16 + hk * 4 + r) * 68
                       + wc * WCN + ni * 16 + hm] = f2bfu(acc[mi][ni][r]);
        __syncthreads();
        ushort* Cp = Cb + (size_t)blockIdx.z * Mrows * ldc;
        #pragma unroll
        for (int it = 0; it < 8; ++it) {
            int i = it * 1024 + tid * 4;
            int row = i >> 6, col = i & 63;
            *(ushort4*)(Cp + (size_t)(m0 + row) * ldc + n0 + col) =
                *(const ushort4*)&Ls[row * 68 + col];
        }
    }
}

// ---------------- MFMA flash attention v3 (unchanged) ----------------
__global__ __launch_bounds__(256) void attn_mfma(
    const ushort* __restrict__ q, const ushort* __restrict__ ksrc,
    const ushort* __restrict__ vtsrc, ushort* __restrict__ cat)
{
    int g = blockIdx.x;
    int h = g >> 1, b = g & 1;
    const ushort* qg  = q     + (size_t)g * Tn * DHn;
    const ushort* kg  = ksrc  + (size_t)g * Tn * DHn;
    const ushort* vtg = vtsrc + (size_t)g * DHn * Tn;   // [d][t]
    int tid = threadIdx.x, wave = tid >> 6, lane = tid & 63;
    int m = lane & 15, gq = lane >> 4;

    __shared__ short Ks[4096];      // [key(64)][d(64)] swizzled
    __shared__ short Vt[4096];      // [d(64)][key(64)] swizzled
    __shared__ short Ps[4][1024];   // per-wave [q(16)][key(64)] swizzled

    int R  = tid >> 2;   // staging row 0..63
    int c2 = tid & 3;    // staging 16-elem chunk

    #pragma unroll 1
    for (int phase = 0; phase < 2; ++phase) {
        int qt = phase ? (31 - (int)blockIdx.y) : (int)blockIdx.y;
        int q0 = qt * 64;

        bf16x8 qf[2];
        {
            const ushort* qp = qg + (size_t)(q0 + wave * 16 + m) * DHn + gq * 8;
            qf[0] = *(const bf16x8*)(qp);
            qf[1] = *(const bf16x8*)(qp + 32);
        }
        f32x4 o[4];
        #pragma unroll
        for (int i = 0; i < 4; ++i) o[i] = (f32x4){0.f, 0.f, 0.f, 0.f};
        float lsum[4] = {0.f, 0.f, 0.f, 0.f};

        for (int kt = 0; kt <= qt; ++kt) {
            int k0 = kt * 64;
            __syncthreads();
            {   // stage K tile [key][d] and V^T tile [d][key], both b128 swizzled
                const ushort* ksp = kg  + (size_t)(k0 + R) * DHn + c2 * 16;
                const ushort* vsp = vtg + (size_t)R * Tn + k0 + c2 * 16;
                bf16x8 f0 = *(const bf16x8*)(ksp);
                bf16x8 f1 = *(const bf16x8*)(ksp + 8);
                bf16x8 v0 = *(const bf16x8*)(vsp);
                bf16x8 v1 = *(const bf16x8*)(vsp + 8);
                *(bf16x8*)&Ks[R * 64 + (((c2 * 2    ) ^ (R & 7)) << 3)] = f0;
                *(bf16x8*)&Ks[R * 64 + (((c2 * 2 + 1) ^ (R & 7)) << 3)] = f1;
                *(bf16x8*)&Vt[R * 64 + (((c2 * 2    ) ^ (R & 7)) << 3)] = v0;
                *(bf16x8*)&Vt[R * 64 + (((c2 * 2 + 1) ^ (R & 7)) << 3)] = v1;
            }
            __syncthreads();

            bool diag = (kt == qt);
            float ps[4][4];
            #pragma unroll
            for (int ct = 0; ct < 4; ++ct) {
                if (diag && ct > wave) {   // fully masked sub-tile
                    ps[ct][0] = ps[ct][1] = ps[ct][2] = ps[ct][3] = 0.f;
                    continue;
                }
                f32x4 acc = (f32x4){0.f, 0.f, 0.f, 0.f};
                int row = ct * 16 + m;     // key within tile
                #pragma unroll
                for (int db = 0; db < 2; ++db) {
                    bf16x8 kf = *(const bf16x8*)&Ks[row * 64 + (((db * 4 + gq) ^ (row & 7)) << 3)];
                    acc = __builtin_amdgcn_mfma_f32_16x16x32_bf16(qf[db], kf, acc, 0, 0, 0);
                }
                #pragma unroll
                for (int r = 0; r < 4; ++r) {
                    float p;
                    if (diag && (ct * 16 + m) > (wave * 16 + gq * 4 + r)) {
                        p = 0.f;
                    } else {
                        p = __expf(acc[r] * 0.125f);   // 1/sqrt(64)
                    }
                    ps[ct][r] = p;
                    lsum[r] += p;
                }
            }

            // P (C-layout) -> LDS -> A-layout fragments (per-wave buffer)
            #pragma unroll
            for (int ct = 0; ct < 4; ++ct)
                #pragma unroll
                for (int r = 0; r < 4; ++r) {
                    int row = gq * 4 + r;
                    Ps[wave][row * 64 + ((((ct * 2 + (m >> 3)) ^ (row & 7)) << 3) | (m & 7))] =
                        f2bf(ps[ct][r]);
                }
            bf16x8 pf[2];
            #pragma unroll
            for (int db2 = 0; db2 < 2; ++db2)
                pf[db2] = *(const bf16x8*)&Ps[wave][m * 64 + (((db2 * 4 + gq) ^ (m & 7)) << 3)];

            #pragma unroll
            for (int ct2 = 0; ct2 < 4; ++ct2) {
                int row = ct2 * 16 + m;   // d index
                #pragma unroll
                for (int db2 = 0; db2 < 2; ++db2) {
                    bf16x8 vf = *(const bf16x8*)&Vt[row * 64 + (((db2 * 4 + gq) ^ (row & 7)) << 3)];
                    o[ct2] = __builtin_amdgcn_mfma_f32_16x16x32_bf16(pf[db2], vf, o[ct2], 0, 0, 0);
                }
            }
        }

        // epilogue: reduce l across the 16-lane row group, scale, quirk write
        float inv[4];
        #pragma unroll
        for (int r = 0; r < 4; ++r) {
            float l = lsum[r];
            l += __shfl_xor(l, 1);
            l += __shfl_xor(l, 2);
            l += __shfl_xor(l, 4);
            l += __shfl_xor(l, 8);
            inv[r] = 1.0f / l;
        }
        size_t base = (size_t)b * Tn * En + (size_t)h * 64 + (size_t)qt * En
                    + wave * 16 + gq * 4;
        #pragma unroll
        for (int ct2 = 0; ct2 < 4; ++ct2) {
            int d = ct2 * 16 + m;
            #pragma unroll
            for (int r = 0; r < 4; ++r)
                cat[base + (size_t)d * 32 * En + r] = f2bfu(o[ct2][r] * inv[r]);
        }
    }
}

extern "C" void kernel_launch(void* const* d_in, const int* in_sizes, int n_in,
                              void* d_out, int out_size, void* d_ws, size_t ws_size,
                              hipStream_t stream) {
    const float* x     = (const float*)d_in[0];
    const float* Wq    = (const float*)d_in[1];
    const float* Wk    = (const float*)d_in[2];
    const float* Wv    = (const float*)d_in[3];
    const float* fc_w  = (const float*)d_in[4];
    const float* fc_b  = (const float*)d_in[5];
    const float* ln1_s = (const float*)d_in[6];
    const float* ln1_b = (const float*)d_in[7];
    const float* ln2_s = (const float*)d_in[8];
    const float* ln2_b = (const float*)d_in[9];
    const float* ff_w1 = (const float*)d_in[10];
    const float* ff_b1 = (const float*)d_in[11];
    const float* ff_w2 = (const float*)d_in[12];
    const float* ff_b2 = (const float*)d_in[13];
    float* out = (float*)d_out;
    (void)in_sizes; (void)n_in; (void)out_size; (void)ws_size;

    const size_t MB = 1048576;
    char* w8 = (char*)d_ws;
    ushort* S0   = (ushort*)(w8 + 0 * MB);    // xn_bf / cat_bf (8MB)
    ushort* kb   = (ushort*)(w8 + 8 * MB);    // k bf16 (8MB)
    ushort* vtb  = (ushort*)(w8 + 16 * MB);   // v^T bf16 [g][d][t] (8MB)
    ushort* qb   = (ushort*)(w8 + 24 * MB);   // q bf16 / ynb_bf (8MB)
    ushort* hb   = (ushort*)(w8 + 32 * MB);   // h bf16 (8MB)
    ushort* Pfc  = (ushort*)(w8 + 48 * MB);   // fc partials 2x8MB bf16
    ushort* y1   = (ushort*)(w8 + 48 * MB);   // gelu out bf16 (32MB) reuses Pfc
    ushort* Pff2 = (ushort*)(w8 + 0 * MB);    // ff2 partials 2x8MB (S0..vtb dead)
    ushort* wqkv = (ushort*)(w8 + 80 * MB);   // [3072][1024] (6MB)
    ushort* wfc  = (ushort*)(w8 + 86 * MB);   // [1024][1024] (2MB)
    ushort* wf1  = (ushort*)(w8 + 88 * MB);   // [4096][1024] (8MB)
    ushort* wf2  = (ushort*)(w8 + 96 * MB);   // [1024][4096] (8MB) -> 104MB total

    // unified weight prep (all four transposes, one dispatch)
    prep_w<<<dim3(3072), 256, 0, stream>>>(
        Wq, Wk, Wv, fc_w, ff_w1, ff_w2, wqkv, wfc, wf1, wf2);

    // LN1 -> xn (bf16)
    ln_kernel<<<dim3(Mrows), 256, 0, stream>>>(x, ln1_s, ln1_b, S0);
    // QKV: [4096,1024] x [3072,1024]^T, LDS-bounced coalesced epilogue
    gemm_bf16<2, 128><<<dim3(32, 24), 256, 0, stream>>>(
        S0, En, wqkv, En, En, nullptr, nullptr, 0, qb, kb, vtb);
    // attention -> cat (bf16, quirk layout), reuses S0
    attn_mfma<<<dim3(Hn * Bn, 16), 256, 0, stream>>>(qb, kb, vtb, S0);
    // fc split-K=2: bf16 partials (2 x 8MB at Pfc)
    gemm_bf16<3, 64><<<dim3(32, 16, 2), 256, 0, stream>>>(
        S0, En, wfc, En, En / 2, nullptr, Pfc, En, nullptr, nullptr, nullptr);
    // reduce + bias + resid(x) -> hb (bf16), fused LN2 -> ynb (qb)
    ln2_fuse<<<dim3(Mrows), 256, 0, stream>>>(
        Pfc, Pfc + (size_t)Mrows * En, fc_b, x, ln2_s, ln2_b, hb, qb);
    // ff1: y1 = gelu(ynb @ ff_w1 + ff_b1)  (bf16 out), 128x128 tile, 1024 blk
    gemm_bf16<1, 128><<<dim3(32, 32), 256, 0, stream>>>(
        qb, En, wf1, En, En, ff_b1, y1, 4 * En, nullptr, nullptr, nullptr);
    // ff2 split-K=2: bf16 partials (2 x 8MB at Pff2)
    gemm_bf16<3, 64><<<dim3(32, 16, 2), 256, 0, stream>>>(
        y1, 4 * En, wf2, 4 * En, 2 * En, nullptr, Pff2, En, nullptr, nullptr, nullptr);
    // reduce + bias + resid(h bf16) -> out
    ff2_reduce<<<dim3(Mrows), 256, 0, stream>>>(
        Pff2, Pff2 + (size_t)Mrows * En, ff_b2, hb, out);
}

// Round 12
// 332.115 us; speedup vs baseline: 1.1304x; 1.0628x over previous
//
#include <hip/hip_runtime.h>

// Transformer block. B=2 T=2048 E=1024 H=16 DH=64.
// R12: ff1 (MODE 1) epilogue gets the per-wave quadrant LDS bounce -> 128B
// contiguous stores (was scalar ushort stores, 2.2x write amplification:
// WRITE 70MB on a 32MB output). Everything else unchanged from R11.

#define En 1024
#define Hn 16
#define DHn 64
#define Bn 2
#define Tn 2048
#define Mrows 4096  // B*T

typedef __attribute__((ext_vector_type(8))) short bf16x8;
typedef __attribute__((ext_vector_type(4))) float f32x4;

__device__ __forceinline__ short f2bf(float f) {
    unsigned u = __float_as_uint(f);
    u += 0x7FFFu + ((u >> 16) & 1u);   // round-to-nearest-even
    return (short)(u >> 16);
}
__device__ __forceinline__ ushort f2bfu(float f) {
    unsigned u = __float_as_uint(f);
    u += 0x7FFFu + ((u >> 16) & 1u);
    return (ushort)(u >> 16);
}
__device__ __forceinline__ float bf2f(ushort u) {
    return __uint_as_float((unsigned)u << 16);
}

// gelu = 0.5*x*(1+tanh(u)) = x * t/(t+1), t = exp(2u); u = c*x + 0.044715*x^3
__device__ __forceinline__ float gelu_f(float x) {
    float u = 0.79788456080286535588f * x + 0.044715f * x * x * x;
    float t = __expf(2.0f * u);
    return x * t / (t + 1.0f);
}

// async global->LDS, 16B per lane; LDS dest = wave-uniform base + lane*16
__device__ __forceinline__ void load_lds16(const void* g, void* l) {
    __builtin_amdgcn_global_load_lds(
        (const __attribute__((address_space(1))) unsigned int*)(uintptr_t)g,
        (__attribute__((address_space(3))) unsigned int*)(uintptr_t)l,
        16, 0, 0);
}

// ---------------- LayerNorm: one block per row, bf16 out ----------------
__global__ __launch_bounds__(256) void ln_kernel(
    const float* __restrict__ in, const float* __restrict__ sc,
    const float* __restrict__ sh, ushort* __restrict__ out)
{
    int row = blockIdx.x;
    int tid = threadIdx.x;
    float4 v = ((const float4*)(in + (size_t)row * En))[tid];
    float s  = v.x + v.y + v.z + v.w;
    float s2 = v.x*v.x + v.y*v.y + v.z*v.z + v.w*v.w;
    #pragma unroll
    for (int off = 32; off > 0; off >>= 1) {
        s  += __shfl_down(s,  off);
        s2 += __shfl_down(s2, off);
    }
    __shared__ float red[2][4];
    int wave = tid >> 6, lane = tid & 63;
    if (lane == 0) { red[0][wave] = s; red[1][wave] = s2; }
    __syncthreads();
    s  = red[0][0] + red[0][1] + red[0][2] + red[0][3];
    s2 = red[1][0] + red[1][1] + red[1][2] + red[1][3];
    float mean = s * (1.0f / En);
    float var  = s2 * (1.0f / En) - mean * mean;
    float r = rsqrtf(var + 1e-5f);
    float4 scv = ((const float4*)sc)[tid];
    float4 shv = ((const float4*)sh)[tid];
    ushort4 o;
    o.x = f2bfu(scv.x * (v.x - mean) * r + shv.x);
    o.y = f2bfu(scv.y * (v.y - mean) * r + shv.y);
    o.z = f2bfu(scv.z * (v.z - mean) * r + shv.z);
    o.w = f2bfu(scv.w * (v.w - mean) * r + shv.w);
    ((ushort4*)(out + (size_t)row * En))[tid] = o;
}

// ---- fc split-K reduce (bf16 partials) + residual + LN2; h stored bf16 ----
__global__ __launch_bounds__(256) void ln2_fuse(
    const ushort* __restrict__ P0, const ushort* __restrict__ P1,
    const float* __restrict__ bias, const float* __restrict__ x,
    const float* __restrict__ sc, const float* __restrict__ sh,
    ushort* __restrict__ hb, ushort* __restrict__ ynb)
{
    int row = blockIdx.x, tid = threadIdx.x;
    size_t idx = (size_t)row * 256 + tid;
    ushort4 a = ((const ushort4*)P0)[idx];
    ushort4 b = ((const ushort4*)P1)[idx];
    float4 bi = ((const float4*)bias)[tid];
    float4 xr = ((const float4*)x)[idx];
    float4 v;
    v.x = bf2f(a.x) + bf2f(b.x) + bi.x + xr.x;
    v.y = bf2f(a.y) + bf2f(b.y) + bi.y + xr.y;
    v.z = bf2f(a.z) + bf2f(b.z) + bi.z + xr.z;
    v.w = bf2f(a.w) + bf2f(b.w) + bi.w + xr.w;
    ushort4 hv;
    hv.x = f2bfu(v.x); hv.y = f2bfu(v.y); hv.z = f2bfu(v.z); hv.w = f2bfu(v.w);
    ((ushort4*)hb)[idx] = hv;
    float s  = v.x + v.y + v.z + v.w;
    float s2 = v.x*v.x + v.y*v.y + v.z*v.z + v.w*v.w;
    #pragma unroll
    for (int off = 32; off > 0; off >>= 1) {
        s  += __shfl_down(s,  off);
        s2 += __shfl_down(s2, off);
    }
    __shared__ float red[2][4];
    int wave = tid >> 6, lane = tid & 63;
    if (lane == 0) { red[0][wave] = s; red[1][wave] = s2; }
    __syncthreads();
    s  = red[0][0] + red[0][1] + red[0][2] + red[0][3];
    s2 = red[1][0] + red[1][1] + red[1][2] + red[1][3];
    float mean = s * (1.0f / En);
    float var  = s2 * (1.0f / En) - mean * mean;
    float r = rsqrtf(var + 1e-5f);
    float4 scv = ((const float4*)sc)[tid];
    float4 shv = ((const float4*)sh)[tid];
    ushort4 o;
    o.x = f2bfu(scv.x * (v.x - mean) * r + shv.x);
    o.y = f2bfu(scv.y * (v.y - mean) * r + shv.y);
    o.z = f2bfu(scv.z * (v.z - mean) * r + shv.z);
    o.w = f2bfu(scv.w * (v.w - mean) * r + shv.w);
    ((ushort4*)ynb)[idx] = o;
}

// ---- ff2 split-K reduce (bf16 partials) + bias + residual(bf16 h) -> out ----
__global__ __launch_bounds__(256) void ff2_reduce(
    const ushort* __restrict__ P0, const ushort* __restrict__ P1,
    const float* __restrict__ bias, const ushort* __restrict__ hb,
    float* __restrict__ out)
{
    int tid = threadIdx.x;
    size_t i = (size_t)blockIdx.x * 256 + tid;
    ushort4 a = ((const ushort4*)P0)[i];
    ushort4 b = ((const ushort4*)P1)[i];
    float4 bi = ((const float4*)bias)[tid];
    ushort4 hu = ((const ushort4*)hb)[i];
    float4 o;
    o.x = bf2f(a.x) + bf2f(b.x) + bi.x + bf2f(hu.x);
    o.y = bf2f(a.y) + bf2f(b.y) + bi.y + bf2f(hu.y);
    o.z = bf2f(a.z) + bf2f(b.z) + bi.z + bf2f(hu.z);
    o.w = bf2f(a.w) + bf2f(b.w) + bi.w + bf2f(hu.w);
    ((float4*)out)[i] = o;
}

// ------- unified weight prep: all four transposes in one dispatch ---------
// out[n*ldo + k] = bf16(in[k*N + n]), 64x64 tiles.
__global__ __launch_bounds__(256) void prep_w(
    const float* __restrict__ Wq, const float* __restrict__ Wk,
    const float* __restrict__ Wv, const float* __restrict__ fc_w,
    const float* __restrict__ ff_w1, const float* __restrict__ ff_w2,
    ushort* __restrict__ wqkv, ushort* __restrict__ wfc,
    ushort* __restrict__ wf1, ushort* __restrict__ wf2)
{
    int bid = blockIdx.x;
    const float* in; ushort* out; int N, ldo, k0, n0;
    if (bid < 768) {                       // qkv: 48 z-slices x 16 k-blocks
        int z = bid >> 4, kb = bid & 15;
        int sel = z / 16, h = z % 16;
        in  = (sel == 0 ? Wq : sel == 1 ? Wk : Wv) + (size_t)h * En * DHn;
        out = wqkv + (size_t)(sel * 1024 + h * 64) * En;
        N = DHn; ldo = En; k0 = kb * 64; n0 = 0;
    } else if (bid < 1024) {               // fc_w: 16x16
        int b2 = bid - 768;
        in = fc_w; out = wfc; N = En; ldo = En;
        k0 = (b2 & 15) * 64; n0 = (b2 >> 4) * 64;
    } else if (bid < 2048) {               // ff_w1: 16 k x 64 n
        int b2 = bid - 1024;
        in = ff_w1; out = wf1; N = 4 * En; ldo = En;
        k0 = (b2 & 15) * 64; n0 = (b2 >> 4) * 64;
    } else {                               // ff_w2: 64 k x 16 n
        int b2 = bid - 2048;
        in = ff_w2; out = wf2; N = En; ldo = 4 * En;
        k0 = (b2 & 63) * 64; n0 = (b2 >> 6) * 64;
    }
    __shared__ float t[64][65];
    int tid = threadIdx.x, r = tid >> 4, c4 = (tid & 15) * 4;
    #pragma unroll
    for (int i = 0; i < 4; ++i) {
        float4 v = *(const float4*)(in + (size_t)(k0 + r + i * 16) * N + n0 + c4);
        t[r + i * 16][c4 + 0] = v.x; t[r + i * 16][c4 + 1] = v.y;
        t[r + i * 16][c4 + 2] = v.z; t[r + i * 16][c4 + 3] = v.w;
    }
    __syncthreads();
    #pragma unroll
    for (int i = 0; i < 4; ++i) {
        int n = r + i * 16;
        ushort4 u;
        u.x = f2bfu(t[c4 + 0][n]); u.y = f2bfu(t[c4 + 1][n]);
        u.z = f2bfu(t[c4 + 2][n]); u.w = f2bfu(t[c4 + 3][n]);
        *(ushort4*)(out + (size_t)(n0 + n) * ldo + k0 + c4) = u;
    }
}

// ---------------- bf16 MFMA GEMM: C[M][N] = A[M][K] * Bt[N][K]^T -----------
// 128 x TN tile, BK=64, slot = j ^ (r&7) XOR swizzle.
// MODE 1: Cb = bf16(gelu(acc + bias)); per-wave quadrant LDS bounce (TN=128)
// MODE 2: qkv; per-wave 64x64 quadrant bounced through LDS, coalesced stores
// MODE 3: split-K partial in bf16: Cb + z*M*ldc, LDS-bounced full-line stores
template<int MODE, int TN>
__global__ __launch_bounds__(256) void gemm_bf16(
    const ushort* __restrict__ A, int lda,
    const ushort* __restrict__ Bt, int ldb, int Kloop,
    const float* __restrict__ bias,
    ushort* __restrict__ Cb, int ldc,
    ushort* __restrict__ qo, ushort* __restrict__ ko, ushort* __restrict__ vo)
{
    constexpr int WCN = TN / 2;        // wave n-extent
    constexpr int NI  = WCN / 16;      // 16-col blocks per wave
    constexpr int BIW = TN * 8 / 256;  // B staging instrs per wave
    constexpr int STAGE = 128 * 64 + TN * 64;
    constexpr int BOUNCE = (MODE == 2 || MODE == 1) ? 4 * 64 * 68
                         : (MODE == 3 ? 128 * 68 : 0);
    constexpr int SMEMN = STAGE > BOUNCE ? STAGE : BOUNCE;
    __shared__ ushort smem[SMEMN];
    ushort* As = smem;
    ushort* Bs = smem + 128 * 64;
    int tid = threadIdx.x, wv = tid >> 6, lid = tid & 63;
    int m0 = blockIdx.x * 128, n0 = blockIdx.y * TN;
    int koff = blockIdx.z * Kloop;
    int wr = wv >> 1, wc = wv & 1;
    int hm = lid & 15, hk = lid >> 4;

    f32x4 acc[4][NI];
    #pragma unroll
    for (int i = 0; i < 4; ++i)
        #pragma unroll
        for (int j = 0; j < NI; ++j) acc[i][j] = (f32x4){0.f, 0.f, 0.f, 0.f};

    const ushort* Abase = A + (size_t)m0 * lda + koff;
    const ushort* Bbase = Bt + (size_t)n0 * ldb + koff;

    for (int k0 = 0; k0 < Kloop; k0 += 64) {
        __syncthreads();
        #pragma unroll
        for (int i = 0; i < 4; ++i) {       // A: 1024 chunks, 4/lane
            int c = wv * 256 + i * 64 + lid;
            int r = c >> 3, s = c & 7;
            int j = s ^ (r & 7);            // source k-chunk for this LDS slot
            load_lds16(Abase + (size_t)r * lda + k0 + j * 8,
                       &As[(wv * 256 + i * 64) * 8]);
        }
        #pragma unroll
        for (int i = 0; i < BIW; ++i) {
            int c = wv * (BIW * 64) + i * 64 + lid;
            int r = c >> 3, s = c & 7;
            int j = s ^ (r & 7);
            load_lds16(Bbase + (size_t)r * ldb + k0 + j * 8,
                       &Bs[(wv * (BIW * 64) + i * 64) * 8]);
        }
        __syncthreads();
        #pragma unroll
        for (int kk = 0; kk < 2; ++kk) {
            bf16x8 af[4], bfr[NI];
            #pragma unroll
            for (int mi = 0; mi < 4; ++mi) {
                int r = wr * 64 + mi * 16 + hm;
                int slot = ((kk << 2) | hk) ^ (r & 7);
                af[mi] = *(const bf16x8*)&As[(r * 8 + slot) * 8];
            }
            #pragma unroll
            for (int ni = 0; ni < NI; ++ni) {
                int r = wc * WCN + ni * 16 + hm;
                int slot = ((kk << 2) | hk) ^ (r & 7);
                bfr[ni] = *(const bf16x8*)&Bs[(r * 8 + slot) * 8];
            }
            #pragma unroll
            for (int mi = 0; mi < 4; ++mi)
                #pragma unroll
                for (int ni = 0; ni < NI; ++ni)
                    acc[mi][ni] = __builtin_amdgcn_mfma_f32_16x16x32_bf16(
                        af[mi], bfr[ni], acc[mi][ni], 0, 0, 0);
        }
    }

    int colbase = n0 + wc * WCN + hm;
    int rowbase = m0 + wr * 64 + hk * 4;
    if (MODE == 1) {
        // gelu + per-wave quadrant bounce -> 128B contiguous stores (TN=128)
        __syncthreads();   // staging LDS reads complete
        ushort* Ls = smem + wv * (64 * 68);
        #pragma unroll
        for (int ni = 0; ni < NI; ++ni) {
            int col = colbase + ni * 16;
            float bb = bias[col];
            #pragma unroll
            for (int mi = 0; mi < 4; ++mi)
                #pragma unroll
                for (int r = 0; r < 4; ++r)
                    Ls[(mi * 16 + hk * 4 + r) * 68 + ni * 16 + hm] =
                        f2bfu(gelu_f(acc[mi][ni][r] + bb));
        }
        ushort* outp = Cb + (size_t)(m0 + wr * 64) * ldc + n0 + wc * 64;
        int dcol = hm * 4;
        #pragma unroll
        for (int i = 0; i < 16; ++i) {
            int t = hk + i * 4;
            *(ushort4*)(outp + (size_t)t * ldc + dcol) =
                *(const ushort4*)&Ls[t * 68 + dcol];
        }
    } else if (MODE == 2) {
        // per-wave 64x64 quadrant -> LDS bounce -> coalesced ushort4 stores
        __syncthreads();   // all waves done reading staging LDS
        ushort* Ls = smem + wv * (64 * 68);
        int col0 = n0 + wc * 64;            // quadrant base (64 cols = 1 head)
        int sel = col0 >> 10, h = (col0 & 1023) >> 6;
        if (sel < 2) {
            // LDS layout [t][d], pitch 68
            #pragma unroll
            for (int ni = 0; ni < NI; ++ni)
                #pragma unroll
                for (int mi = 0; mi < 4; ++mi)
                    #pragma unroll
                    for (int r = 0; r < 4; ++r)
                        Ls[(mi * 16 + hk * 4 + r) * 68 + ni * 16 + hm] =
                            f2bfu(acc[mi][ni][r]);
            ushort* outp = (sel == 0 ? qo : ko) + (size_t)h * (Mrows * DHn);
            int dcol = hm * 4;
            #pragma unroll
            for (int i = 0; i < 16; ++i) {
                int t = hk + i * 4;
                *(ushort4*)(outp + (size_t)(m0 + wr * 64 + t) * DHn + dcol) =
                    *(const ushort4*)&Ls[t * 68 + dcol];
            }
        } else {
            // LDS layout [d][t], pitch 68
            #pragma unroll
            for (int ni = 0; ni < NI; ++ni)
                #pragma unroll
                for (int mi = 0; mi < 4; ++mi)
                    #pragma unroll
                    for (int r = 0; r < 4; ++r)
                        Ls[(ni * 16 + hm) * 68 + mi * 16 + hk * 4 + r] =
                            f2bfu(acc[mi][ni][r]);
            int bb2 = m0 >> 11;                 // batch of this row-tile
            int t0 = (m0 & 2047) + wr * 64;
            ushort* outp = vo + ((size_t)((h * 2 + bb2) * 64)) * Tn + t0;
            int tcol = hm * 4;
            #pragma unroll
            for (int i = 0; i < 16; ++i) {
                int d = hk + i * 4;
                *(ushort4*)(outp + (size_t)d * Tn + tcol) =
                    *(const ushort4*)&Ls[d * 68 + tcol];
            }
        }
    } else {
        // bf16 partials, bounced through LDS for full-line coalesced stores
        __syncthreads();   // staging LDS reads complete
        ushort* Ls = smem; // [128][TN] pitch 68 (TN==64)
        #pragma unroll
        for (int ni = 0; ni < NI; ++ni)
            #pragma unroll
            for (int mi = 0; mi < 4; ++mi)
                #pragma unroll
                for (int r = 0; r < 4; ++r)
                    Ls[(wr * 64 + mi * 16 + hk * 4 + r) * 68
                       + wc * WCN + ni * 16 + hm] = f2bfu(acc[mi][ni][r]);
        __syncthreads();
        ushort* Cp = Cb + (size_t)blockIdx.z * Mrows * ldc;
        #pragma unroll
        for (int it = 0; it < 8; ++it) {
            int i = it * 1024 + tid * 4;
            int row = i >> 6, col = i & 63;
            *(ushort4*)(Cp + (size_t)(m0 + row) * ldc + n0 + col) =
                *(const ushort4*)&Ls[row * 68 + col];
        }
    }
}

// ---------------- MFMA flash attention v3 (unchanged) ----------------
__global__ __launch_bounds__(256) void attn_mfma(
    const ushort* __restrict__ q, const ushort* __restrict__ ksrc,
    const ushort* __restrict__ vtsrc, ushort* __restrict__ cat)
{
    int g = blockIdx.x;
    int h = g >> 1, b = g & 1;
    const ushort* qg  = q     + (size_t)g * Tn * DHn;
    const ushort* kg  = ksrc  + (size_t)g * Tn * DHn;
    const ushort* vtg = vtsrc + (size_t)g * DHn * Tn;   // [d][t]
    int tid = threadIdx.x, wave = tid >> 6, lane = tid & 63;
    int m = lane & 15, gq = lane >> 4;

    __shared__ short Ks[4096];      // [key(64)][d(64)] swizzled
    __shared__ short Vt[4096];      // [d(64)][key(64)] swizzled
    __shared__ short Ps[4][1024];   // per-wave [q(16)][key(64)] swizzled

    int R  = tid >> 2;   // staging row 0..63
    int c2 = tid & 3;    // staging 16-elem chunk

    #pragma unroll 1
    for (int phase = 0; phase < 2; ++phase) {
        int qt = phase ? (31 - (int)blockIdx.y) : (int)blockIdx.y;
        int q0 = qt * 64;

        bf16x8 qf[2];
        {
            const ushort* qp = qg + (size_t)(q0 + wave * 16 + m) * DHn + gq * 8;
            qf[0] = *(const bf16x8*)(qp);
            qf[1] = *(const bf16x8*)(qp + 32);
        }
        f32x4 o[4];
        #pragma unroll
        for (int i = 0; i < 4; ++i) o[i] = (f32x4){0.f, 0.f, 0.f, 0.f};
        float lsum[4] = {0.f, 0.f, 0.f, 0.f};

        for (int kt = 0; kt <= qt; ++kt) {
            int k0 = kt * 64;
            __syncthreads();
            {   // stage K tile [key][d] and V^T tile [d][key], both b128 swizzled
                const ushort* ksp = kg  + (size_t)(k0 + R) * DHn + c2 * 16;
                const ushort* vsp = vtg + (size_t)R * Tn + k0 + c2 * 16;
                bf16x8 f0 = *(const bf16x8*)(ksp);
                bf16x8 f1 = *(const bf16x8*)(ksp + 8);
                bf16x8 v0 = *(const bf16x8*)(vsp);
                bf16x8 v1 = *(const bf16x8*)(vsp + 8);
                *(bf16x8*)&Ks[R * 64 + (((c2 * 2    ) ^ (R & 7)) << 3)] = f0;
                *(bf16x8*)&Ks[R * 64 + (((c2 * 2 + 1) ^ (R & 7)) << 3)] = f1;
                *(bf16x8*)&Vt[R * 64 + (((c2 * 2    ) ^ (R & 7)) << 3)] = v0;
                *(bf16x8*)&Vt[R * 64 + (((c2 * 2 + 1) ^ (R & 7)) << 3)] = v1;
            }
            __syncthreads();

            bool diag = (kt == qt);
            float ps[4][4];
            #pragma unroll
            for (int ct = 0; ct < 4; ++ct) {
                if (diag && ct > wave) {   // fully masked sub-tile
                    ps[ct][0] = ps[ct][1] = ps[ct][2] = ps[ct][3] = 0.f;
                    continue;
                }
                f32x4 acc = (f32x4){0.f, 0.f, 0.f, 0.f};
                int row = ct * 16 + m;     // key within tile
                #pragma unroll
                for (int db = 0; db < 2; ++db) {
                    bf16x8 kf = *(const bf16x8*)&Ks[row * 64 + (((db * 4 + gq) ^ (row & 7)) << 3)];
                    acc = __builtin_amdgcn_mfma_f32_16x16x32_bf16(qf[db], kf, acc, 0, 0, 0);
                }
                #pragma unroll
                for (int r = 0; r < 4; ++r) {
                    float p;
                    if (diag && (ct * 16 + m) > (wave * 16 + gq * 4 + r)) {
                        p = 0.f;
                    } else {
                        p = __expf(acc[r] * 0.125f);   // 1/sqrt(64)
                    }
                    ps[ct][r] = p;
                    lsum[r] += p;
                }
            }

            // P (C-layout) -> LDS -> A-layout fragments (per-wave buffer)
            #pragma unroll
            for (int ct = 0; ct < 4; ++ct)
                #pragma unroll
                for (int r = 0; r < 4; ++r) {
                    int row = gq * 4 + r;
                    Ps[wave][row * 64 + ((((ct * 2 + (m >> 3)) ^ (row & 7)) << 3) | (m & 7))] =
                        f2bf(ps[ct][r]);
                }
            bf16x8 pf[2];
            #pragma unroll
            for (int db2 = 0; db2 < 2; ++db2)
                pf[db2] = *(const bf16x8*)&Ps[wave][m * 64 + (((db2 * 4 + gq) ^ (m & 7)) << 3)];

            #pragma unroll
            for (int ct2 = 0; ct2 < 4; ++ct2) {
                int row = ct2 * 16 + m;   // d index
                #pragma unroll
                for (int db2 = 0; db2 < 2; ++db2) {
                    bf16x8 vf = *(const bf16x8*)&Vt[row * 64 + (((db2 * 4 + gq) ^ (row & 7)) << 3)];
                    o[ct2] = __builtin_amdgcn_mfma_f32_16x16x32_bf16(pf[db2], vf, o[ct2], 0, 0, 0);
                }
            }
        }

        // epilogue: reduce l across the 16-lane row group, scale, quirk write
        float inv[4];
        #pragma unroll
        for (int r = 0; r < 4; ++r) {
            float l = lsum[r];
            l += __shfl_xor(l, 1);
            l += __shfl_xor(l, 2);
            l += __shfl_xor(l, 4);
            l += __shfl_xor(l, 8);
            inv[r] = 1.0f / l;
        }
        size_t base = (size_t)b * Tn * En + (size_t)h * 64 + (size_t)qt * En
                    + wave * 16 + gq * 4;
        #pragma unroll
        for (int ct2 = 0; ct2 < 4; ++ct2) {
            int d = ct2 * 16 + m;
            #pragma unroll
            for (int r = 0; r < 4; ++r)
                cat[base + (size_t)d * 32 * En + r] = f2bfu(o[ct2][r] * inv[r]);
        }
    }
}

extern "C" void kernel_launch(void* const* d_in, const int* in_sizes, int n_in,
                              void* d_out, int out_size, void* d_ws, size_t ws_size,
                              hipStream_t stream) {
    const float* x     = (const float*)d_in[0];
    const float* Wq    = (const float*)d_in[1];
    const float* Wk    = (const float*)d_in[2];
    const float* Wv    = (const float*)d_in[3];
    const float* fc_w  = (const float*)d_in[4];
    const float* fc_b  = (const float*)d_in[5];
    const float* ln1_s = (const float*)d_in[6];
    const float* ln1_b = (const float*)d_in[7];
    const float* ln2_s = (const float*)d_in[8];
    const float* ln2_b = (const float*)d_in[9];
    const float* ff_w1 = (const float*)d_in[10];
    const float* ff_b1 = (const float*)d_in[11];
    const float* ff_w2 = (const float*)d_in[12];
    const float* ff_b2 = (const float*)d_in[13];
    float* out = (float*)d_out;
    (void)in_sizes; (void)n_in; (void)out_size; (void)ws_size;

    const size_t MB = 1048576;
    char* w8 = (char*)d_ws;
    ushort* S0   = (ushort*)(w8 + 0 * MB);    // xn_bf / cat_bf (8MB)
    ushort* kb   = (ushort*)(w8 + 8 * MB);    // k bf16 (8MB)
    ushort* vtb  = (ushort*)(w8 + 16 * MB);   // v^T bf16 [g][d][t] (8MB)
    ushort* qb   = (ushort*)(w8 + 24 * MB);   // q bf16 / ynb_bf (8MB)
    ushort* hb   = (ushort*)(w8 + 32 * MB);   // h bf16 (8MB)
    ushort* Pfc  = (ushort*)(w8 + 48 * MB);   // fc partials 2x8MB bf16
    ushort* y1   = (ushort*)(w8 + 48 * MB);   // gelu out bf16 (32MB) reuses Pfc
    ushort* Pff2 = (ushort*)(w8 + 0 * MB);    // ff2 partials 2x8MB (S0..vtb dead)
    ushort* wqkv = (ushort*)(w8 + 80 * MB);   // [3072][1024] (6MB)
    ushort* wfc  = (ushort*)(w8 + 86 * MB);   // [1024][1024] (2MB)
    ushort* wf1  = (ushort*)(w8 + 88 * MB);   // [4096][1024] (8MB)
    ushort* wf2  = (ushort*)(w8 + 96 * MB);   // [1024][4096] (8MB) -> 104MB total

    // unified weight prep (all four transposes, one dispatch)
    prep_w<<<dim3(3072), 256, 0, stream>>>(
        Wq, Wk, Wv, fc_w, ff_w1, ff_w2, wqkv, wfc, wf1, wf2);

    // LN1 -> xn (bf16)
    ln_kernel<<<dim3(Mrows), 256, 0, stream>>>(x, ln1_s, ln1_b, S0);
    // QKV: [4096,1024] x [3072,1024]^T, LDS-bounced coalesced epilogue
    gemm_bf16<2, 128><<<dim3(32, 24), 256, 0, stream>>>(
        S0, En, wqkv, En, En, nullptr, nullptr, 0, qb, kb, vtb);
    // attention -> cat (bf16, quirk layout), reuses S0
    attn_mfma<<<dim3(Hn * Bn, 16), 256, 0, stream>>>(qb, kb, vtb, S0);
    // fc split-K=2: bf16 partials (2 x 8MB at Pfc)
    gemm_bf16<3, 64><<<dim3(32, 16, 2), 256, 0, stream>>>(
        S0, En, wfc, En, En / 2, nullptr, Pfc, En, nullptr, nullptr, nullptr);
    // reduce + bias + resid(x) -> hb (bf16), fused LN2 -> ynb (qb)
    ln2_fuse<<<dim3(Mrows), 256, 0, stream>>>(
        Pfc, Pfc + (size_t)Mrows * En, fc_b, x, ln2_s, ln2_b, hb, qb);
    // ff1: y1 = gelu(ynb @ ff_w1 + ff_b1)  (bf16 out), bounced epilogue
    gemm_bf16<1, 128><<<dim3(32, 32), 256, 0, stream>>>(
        qb, En, wf1, En, En, ff_b1, y1, 4 * En, nullptr, nullptr, nullptr);
    // ff2 split-K=2: bf16 partials (2 x 8MB at Pff2)
    gemm_bf16<3, 64><<<dim3(32, 16, 2), 256, 0, stream>>>(
        y1, 4 * En, wf2, 4 * En, 2 * En, nullptr, Pff2, En, nullptr, nullptr, nullptr);
    // reduce + bias + resid(h bf16) -> out
    ff2_reduce<<<dim3(Mrows), 256, 0, stream>>>(
        Pff2, Pff2 + (size_t)Mrows * En, ff_b2, hb, out);
}